// Round 10
// baseline (380.329 us; speedup 1.0000x reference)
//
#include <hip/hip_runtime.h>

// ---------------------------------------------------------------------------
// MatchNet: 3-layer MLP (relu after every layer) -> batched PDHG LP solve.
// Shapes: X[2048,64], W1[64,1024], W2[1024,1024], W3[1024,512], S[64,512].
// Output: x [2048,512] fp32.
//
// R10 (= R9 with vector-element address fix): pdhg in 512-thread blocks
// (8 waves = 2/SIMD). Waves pair up: pair p owns combos [p*16,+16) & cols
// [p*128,+128); sub 0 does Kx chunks 0-7 + KTy t 0-3 + the y_lo update;
// sub 1 does chunks 8-15 + t 4-7. Kx running partials exchanged via LDS.
// Halves per-wave registers -> 2 waves/SIMD latency cover.
// power_iter folded into prep as block 0 (256-thread variant).
// ---------------------------------------------------------------------------

typedef _Float16 half8 __attribute__((ext_vector_type(8)));
typedef __fp16 fp16x2 __attribute__((ext_vector_type(2)));
typedef __fp16 fp16x4 __attribute__((ext_vector_type(4)));
typedef float floatx4 __attribute__((ext_vector_type(4)));
typedef float floatx2 __attribute__((ext_vector_type(2)));

#define BATCH 2048
#define NITERS 60
#define XBS 520   // delta-xbar LDS row stride in halves
#define YLS 72    // delta-ylo  LDS row stride in halves

typedef const __attribute__((address_space(1))) unsigned int* gptr_as1;
typedef __attribute__((address_space(3))) unsigned int* lptr_as3;
__device__ __forceinline__ void gl_lds16(const _Float16* g, _Float16* s) {
    __builtin_amdgcn_global_load_lds((gptr_as1)g, (lptr_as3)s, 16, 0, 0);
}
__device__ __forceinline__ floatx2 pmax0(floatx2 a) {
    return __builtin_elementwise_max(a, floatx2{0.f, 0.f});
}

// ---------------- power iteration for tau, 256-thread variant ------------------
__device__ void power_256(const float* __restrict__ S, float* __restrict__ tau_g) {
    __shared__ float vv[512], ww[64], redp[4];
    int t = threadIdx.x, wv = t >> 6, ln = t & 63;
    unsigned long long rm0 = 0, rm1 = 0, cm0 = 0, cm1 = 0;
    for (int rr = 0; rr < 8; rr++)
        for (int e = 0; e < 8; e++) {
            if (S[(wv * 16 + rr) * 512 + e * 64 + ln] != 0.f) rm0 |= 1ull << (rr * 8 + e);
            if (S[(wv * 16 + 8 + rr) * 512 + e * 64 + ln] != 0.f) rm1 |= 1ull << (rr * 8 + e);
        }
    for (int j = 0; j < 64; j++) {
        if (S[j * 512 + t] != 0.f) cm0 |= 1ull << j;
        if (S[j * 512 + t + 256] != 0.f) cm1 |= 1ull << j;
    }
    vv[t] = 0.044194173824159216f;        // 1/sqrt(512)
    vv[t + 256] = 0.044194173824159216f;
    __syncthreads();
    for (int s = 0; s <= 30; s++) {
        float ve[8];
#pragma unroll
        for (int e = 0; e < 8; e++) ve[e] = vv[e * 64 + ln];
        float pr[16];
#pragma unroll
        for (int rr = 0; rr < 8; rr++) {
            unsigned int b0 = (unsigned int)(rm0 >> (rr * 8)) & 0xffu;
            unsigned int b1 = (unsigned int)(rm1 >> (rr * 8)) & 0xffu;
            float a0 = 0.f, a1 = 0.f;
#pragma unroll
            for (int e = 0; e < 8; e++) {
                a0 += (b0 >> e & 1) ? ve[e] : 0.f;
                a1 += (b1 >> e & 1) ? ve[e] : 0.f;
            }
            pr[rr] = a0; pr[8 + rr] = a1;
        }
#pragma unroll
        for (int o = 32; o > 0; o >>= 1)
#pragma unroll
            for (int rr = 0; rr < 16; rr++) pr[rr] += __shfl_xor(pr[rr], o, 64);
        if (ln < 16) ww[wv * 16 + ln] = pr[ln];
        __syncthreads();
        float u0 = vv[t], u1 = vv[t + 256];
#pragma unroll
        for (int j = 0; j < 64; j++) {
            u0 += (cm0 >> j & 1) ? ww[j] : 0.f;
            u1 += (cm1 >> j & 1) ? ww[j] : 0.f;
        }
        float n2 = (s == 30) ? (vv[t] * u0 + vv[t + 256] * u1) : (u0 * u0 + u1 * u1);
#pragma unroll
        for (int o = 32; o > 0; o >>= 1) n2 += __shfl_xor(n2, o, 64);
        if (ln == 0) redp[wv] = n2;
        __syncthreads();
        float tot = (redp[0] + redp[1]) + (redp[2] + redp[3]);
        if (s == 30) {
            if (t == 0) tau_g[0] = 0.9f / sqrtf(tot);
            return;
        }
        float sq = sqrtf(tot);
        vv[t] = u0 / sq;              // all vv reads completed before redp barrier
        vv[t + 256] = u1 / sq;
        __syncthreads();
    }
}

// ---------------- merged prep: power (blk 0), cast X, W transposes, S frags ----
// bid 0: power. [1,513): Xh. [513,577): W1t. [577,1601): W2t. [1601,2113):
// W3t. [2113,2369): s1f/s2f MFMA fragments of S (pi baked into s1f).
__global__ __launch_bounds__(256) void prep(
    const float* __restrict__ X, _Float16* __restrict__ Xh,
    const float* __restrict__ W1, _Float16* __restrict__ W1t,
    const float* __restrict__ W2, _Float16* __restrict__ W2t,
    const float* __restrict__ W3, _Float16* __restrict__ W3t,
    const float* __restrict__ S, _Float16* __restrict__ s1f,
    _Float16* __restrict__ s2f, float* __restrict__ tau_g) {
    __shared__ float tile[32][33];
    int tid = threadIdx.x;
    int bid = blockIdx.x;
    if (bid == 0) { power_256(S, tau_g); return; }
    bid -= 1;
    if (bid < 512) {
        int i = bid * 256 + tid;
        Xh[i] = (_Float16)X[i];
        return;
    }
    bid -= 512;
    if (bid < 1600) {   // transpose+cast W[K][N] -> Wt[N][K]
        const float* W; _Float16* Wt; int K, N, b;
        if (bid < 64)        { W = W1; Wt = W1t; K = 64;   N = 1024; b = bid; }
        else if (bid < 1088) { W = W2; Wt = W2t; K = 1024; N = 1024; b = bid - 64; }
        else                 { W = W3; Wt = W3t; K = 1024; N = 512;  b = bid - 1088; }
        int nbx = N / 32;
        int n0 = (b % nbx) * 32, k0 = (b / nbx) * 32;
        int tx = tid & 31, ty = tid >> 5;
#pragma unroll
        for (int i = 0; i < 4; i++)
            tile[ty + i * 8][tx] = W[(size_t)(k0 + ty + i * 8) * N + n0 + tx];
        __syncthreads();
#pragma unroll
        for (int i = 0; i < 4; i++)
            Wt[(size_t)(n0 + ty + i * 8) * K + k0 + tx] = (_Float16)tile[tx][ty + i * 8];
        return;
    }
    bid -= 1600;
    int i = bid * 256 + tid;       // 0 .. 65535
    if (i < 4 * 16 * 64 * 8) {     // s1f: B-frag of S^T, k-axis in pi-order
        int j = i & 7, lane = (i >> 3) & 63, kk = (i >> 9) & 15, wc = i >> 13;
        int p = kk * 32 + (lane >> 4) * 8 + j;
        int lmc = (p & 127) >> 3, tc = p & 7;
        int c = (p >> 7) * 128 + tc * 16 + lmc;       // pi^-1
        int m = wc * 16 + (lane & 15);
        s1f[i] = (_Float16)S[m * 512 + c];
    } else {                       // s2f: B-frag of S (k = combos)
        int i2 = i - 4 * 16 * 64 * 8;
        int j = i2 & 7, lane = (i2 >> 3) & 63, c = (i2 >> 9) & 1,
            tt = (i2 >> 10) & 7, wc = i2 >> 13;
        int kc = c * 32 + (lane >> 4) * 8 + j;
        int n = wc * 128 + tt * 16 + (lane & 15);
        s2f[i2] = (_Float16)S[kc * 512 + n];
    }
}

// ---------------- GEMM: out = relu(A[M,K] @ W[K,N] + bias), f16 in, fp32 acc ---
__global__ __launch_bounds__(256) void gemm_relu(
    const _Float16* __restrict__ A, const _Float16* __restrict__ Wt,
    const float* __restrict__ bias, _Float16* __restrict__ outh,
    float* __restrict__ outf, int N, int K) {
    __shared__ __align__(16) _Float16 As[128 * 32];
    __shared__ __align__(16) _Float16 Bs[64 * 32];
    int tid = threadIdx.x;
    int bm = blockIdx.y * 128;
    int bn = blockIdx.x * 64;
    int w = tid >> 6, l = tid & 63;
    int wr = w >> 1, wc = w & 1;
    int lm = l & 15, q = l >> 4;
    floatx4 acc[4][2] = {};

    int sr = l >> 2;
    int sc = (l & 3) * 8;
    const _Float16* ag0 = A + (size_t)(bm + w * 32 + sr) * K + sc;
    const _Float16* ag1 = A + (size_t)(bm + w * 32 + 16 + sr) * K + sc;
    _Float16* as0 = &As[(w * 32) * 32];
    _Float16* as1 = &As[(w * 32 + 16) * 32];
    const _Float16* bg = Wt + (size_t)(bn + w * 16 + sr) * K + sc;
    _Float16* bs = &Bs[(w * 16) * 32];

    for (int k0 = 0; k0 < K; k0 += 32) {
        gl_lds16(ag0 + k0, as0);
        gl_lds16(ag1 + k0, as1);
        gl_lds16(bg + k0, bs);
        __syncthreads();
        half8 af[4], bf[2];
#pragma unroll
        for (int mt = 0; mt < 4; mt++)
            af[mt] = *(const half8*)&As[(wr * 64 + mt * 16 + lm) * 32 + q * 8];
#pragma unroll
        for (int nt = 0; nt < 2; nt++)
            bf[nt] = *(const half8*)&Bs[(wc * 32 + nt * 16 + lm) * 32 + q * 8];
#pragma unroll
        for (int mt = 0; mt < 4; mt++)
#pragma unroll
            for (int nt = 0; nt < 2; nt++)
                acc[mt][nt] = __builtin_amdgcn_mfma_f32_16x16x32_f16(
                    af[mt], bf[nt], acc[mt][nt], 0, 0, 0);
        __syncthreads();
    }
#pragma unroll
    for (int nt = 0; nt < 2; nt++) {
        int col = bn + wc * 32 + nt * 16 + lm;
        float bv = bias[col];
#pragma unroll
        for (int mt = 0; mt < 4; mt++) {
#pragma unroll
            for (int v = 0; v < 4; v++) {
                int row = bm + wr * 64 + mt * 16 + q * 4 + v;
                float val = fmaxf(acc[mt][nt][v] + bv, 0.f);
                if (outh) outh[(size_t)row * N + col] = (_Float16)val;
                else      outf[(size_t)row * N + col] = val;
            }
        }
    }
}

// ---------------- Delta-form MFMA PDHG, 8-wave split, 60 iterations ------------
// Block = 8 batch rows, 512 threads = 8 waves (2/SIMD). Pair p = wave>>1 owns
// combos [p*16,+16) and cols [p*128,+128); sub s = wave&1 owns Kx k-chunks
// [s*8,+8) and KTy t-tiles [s*4,+4) (cols [p*128+s*64,+64)). Kx running
// partials (delta form) exchanged via pa1; sub 0 owns the y_lo update.
__global__ __launch_bounds__(512, 2) void pdhg_mfma(
    const float* __restrict__ Zb, const float* __restrict__ Xf,
    const _Float16* __restrict__ s1f, const _Float16* __restrict__ s2f,
    const float* __restrict__ tau_p, float* __restrict__ out) {
    __shared__ __align__(16) _Float16 xb_d[16 * XBS];
    __shared__ __align__(16) _Float16 yl_d[16 * YLS];
    __shared__ __align__(16) float pa1[8 * 256];   // per-wave Kx running partials
    __shared__ __align__(16) float red[16][8];
    int tid = threadIdx.x;
    int wave = tid >> 6, p = wave >> 1, s = wave & 1;
    int l = tid & 63, lm = l & 15, q = l >> 4;
    int b0 = blockIdx.x * 8;
    bool act = (q < 2);

    // constant S fragments for this sub-wave
    half8 s1[8], s2[4][2];
#pragma unroll
    for (int k = 0; k < 8; k++)
        s1[k] = *(const half8*)&s1f[((p * 16 + s * 8 + k) * 64 + l) * 8];
#pragma unroll
    for (int tt = 0; tt < 4; tt++)
#pragma unroll
        for (int c = 0; c < 2; c++)
            s2[tt][c] = *(const half8*)&s2f[(((p * 8 + s * 4 + tt) * 2 + c) * 64 + l) * 8];

    // paired state over this sub's 64 cols: [vp][tt], rows v = 2vp+c
    floatx2 z2[2][4], x2[2][4], xb2[2][4], yh2[2][4], d2[2][4];
    floatx2 ylo2[2], Bc2[2];
    floatx4 a1p0 = {}, a1p1 = {};   // running S.xbar partial (this sub's chunks)
    floatx4 acc2[4] = {};           // running S^T.ylo (this sub's t-tiles)
    float tau = tau_p[0];
    float sig = tau;
#pragma unroll
    for (int vp = 0; vp < 2; vp++) {
        int r0 = b0 + ((q * 4 + 2 * vp) & 7);
        int r1 = b0 + ((q * 4 + 2 * vp + 1) & 7);
        Bc2[vp] = floatx2{Xf[r0 * 64 + p * 16 + lm], Xf[r1 * 64 + p * 16 + lm]};
        ylo2[vp] = floatx2{0.f, 0.f};
#pragma unroll
        for (int tt = 0; tt < 4; tt++) {
            int cc = p * 128 + (s * 4 + tt) * 16 + lm;
            z2[vp][tt] = floatx2{Zb[(size_t)r0 * 512 + cc], Zb[(size_t)r1 * 512 + cc]};
            x2[vp][tt] = floatx2{0.f, 0.f};
            xb2[vp][tt] = floatx2{0.f, 0.f};
            yh2[vp][tt] = floatx2{0.f, 0.f};
        }
    }
    {
        half8 hz = {0, 0, 0, 0, 0, 0, 0, 0};
        for (int i = tid; i < (16 * XBS) / 8; i += 512)
            *(half8*)&xb_d[i * 8] = hz;
        for (int i = tid; i < 16 * YLS; i += 512)
            yl_d[i] = (_Float16)0.f;
    }
    __syncthreads();

#pragma unroll 1
    for (int it = 0; it < NITERS; ++it) {
        // ---- Kx increment (this sub's 8 chunks) ----
#pragma unroll
        for (int k = 0; k < 8; k++) {
            half8 ad = *(const half8*)&xb_d[lm * XBS + (s * 8 + k) * 32 + q * 8];
            if (k & 1) a1p1 = __builtin_amdgcn_mfma_f32_16x16x32_f16(ad, s1[k], a1p1, 0, 0, 0);
            else       a1p0 = __builtin_amdgcn_mfma_f32_16x16x32_f16(ad, s1[k], a1p0, 0, 0, 0);
        }
        floatx4 own = a1p0 + a1p1;
        // publish running partial for the partner
        {
            int base = wave * 256 + (q * 4) * 16 + lm;
            pa1[base] = own.x;
            pa1[base + 16] = own.y;
            pa1[base + 32] = own.z;
            pa1[base + 48] = own.w;
        }
        __syncthreads();   // [P] partials visible
        if (s == 0) {
            // combine with partner's running partial -> full a1 = S.xbar
            int base = (wave ^ 1) * 256 + (q * 4) * 16 + lm;
            floatx4 a1 = own + floatx4{pa1[base], pa1[base + 16],
                                       pa1[base + 32], pa1[base + 48]};
            // y_lo update + publish delta
#pragma unroll
            for (int vp = 0; vp < 2; vp++) {
                floatx2 av = (vp == 0) ? floatx2{a1.x, a1.y} : floatx2{a1.z, a1.w};
                floatx2 yv = pmax0(ylo2[vp] + sig * (av - Bc2[vp]));
                floatx2 dy = yv - ylo2[vp];
                ylo2[vp] = yv;
                if (act) {
                    fp16x2 pk = __builtin_amdgcn_cvt_pkrtz(dy.x, dy.y);
                    int a0 = (q * 4 + 2 * vp) * YLS + p * 16 + lm;
                    yl_d[a0] = (_Float16)pk[0];
                    yl_d[a0 + YLS] = (_Float16)pk[1];
                }
            }
        }
        __syncthreads();   // [A] delta-y plane ready
        // ---- KTy increment: acc2 += d_y @ S (this sub's 4 t-tiles) ----
        half8 a2d[2];
#pragma unroll
        for (int c = 0; c < 2; c++)
            a2d[c] = *(const half8*)&yl_d[lm * YLS + c * 32 + q * 8];
#pragma unroll
        for (int tt = 0; tt < 4; tt++)
#pragma unroll
            for (int c = 0; c < 2; c++)
                acc2[tt] = __builtin_amdgcn_mfma_f32_16x16x32_f16(a2d[c], s2[tt][c], acc2[tt], 0, 0, 0);
        // ---- packed: y_hi update, d = (x - tau*kty) + (tau - z), norm partials ----
        floatx2 pn2[2] = {floatx2{0.f, 0.f}, floatx2{0.f, 0.f}};
#pragma unroll
        for (int vp = 0; vp < 2; vp++)
#pragma unroll
            for (int tt = 0; tt < 4; tt++) {
                floatx2 accp = (vp == 0) ? floatx2{acc2[tt].x, acc2[tt].y}
                                         : floatx2{acc2[tt].z, acc2[tt].w};
                yh2[vp][tt] = pmax0(yh2[vp][tt] - sig * xb2[vp][tt]);
                floatx2 kty = accp - yh2[vp][tt];
                floatx2 dd = (x2[vp][tt] - tau * kty) + (tau - z2[vp][tt]);
                d2[vp][tt] = dd;
                pn2[vp] += dd * dd;
            }
        float pn[4] = {pn2[0].x, pn2[0].y, pn2[1].x, pn2[1].y};
#pragma unroll
        for (int o = 1; o < 16; o <<= 1)
#pragma unroll
            for (int v = 0; v < 4; v++) pn[v] += __shfl_xor(pn[v], o, 64);
        if (lm == 0)
#pragma unroll
            for (int v = 0; v < 4; v++) red[q * 4 + v][wave] = pn[v];
        __syncthreads();   // [B] norm partials ready
        floatx2 sc2[2];
#pragma unroll
        for (int vp = 0; vp < 2; vp++)
#pragma unroll
            for (int c = 0; c < 2; c++) {
                int v = 2 * vp + c;
                floatx4 r0 = *(const floatx4*)&red[q * 4 + v][0];
                floatx4 r1 = *(const floatx4*)&red[q * 4 + v][4];
                floatx4 rr = r0 + r1;
                float nrm = sqrtf((rr.x + rr.y) + (rr.z + rr.w));
                float sv = fmaxf(1.f - tau / fmaxf(nrm, 1e-12f), 0.f);
                if (c == 0) sc2[vp].x = sv; else sc2[vp].y = sv;
            }
        // ---- packed prox + delta-xbar publish (pi-order: b64 per v) ----
#pragma unroll
        for (int vp = 0; vp < 2; vp++) {
#pragma unroll
            for (int tt = 0; tt < 4; tt++) {
                floatx2 xn = z2[vp][tt] + sc2[vp] * d2[vp][tt];
                floatx2 xbn = 2.f * xn - x2[vp][tt];
                d2[vp][tt] = xbn - xb2[vp][tt];   // reuse d2 as delta
                x2[vp][tt] = xn;
                xb2[vp][tt] = xbn;
            }
            if (act) {
#pragma unroll
                for (int c = 0; c < 2; c++) {
                    fp16x2 p0 = __builtin_amdgcn_cvt_pkrtz(
                        (c == 0) ? d2[vp][0].x : d2[vp][0].y,
                        (c == 0) ? d2[vp][1].x : d2[vp][1].y);
                    fp16x2 p1 = __builtin_amdgcn_cvt_pkrtz(
                        (c == 0) ? d2[vp][2].x : d2[vp][2].y,
                        (c == 0) ? d2[vp][3].x : d2[vp][3].y);
                    fp16x4 hd = __builtin_shufflevector(p0, p1, 0, 1, 2, 3);
                    int v = 2 * vp + c;
                    *(fp16x4*)&xb_d[(q * 4 + v) * XBS + p * 128 + lm * 8 + s * 4] = hd;
                }
            }
        }
        __syncthreads();   // [C] delta-xbar plane ready for next iteration
    }
    if (act)
#pragma unroll
        for (int vp = 0; vp < 2; vp++)
#pragma unroll
            for (int tt = 0; tt < 4; tt++) {
                int cc = p * 128 + (s * 4 + tt) * 16 + lm;
                out[(size_t)(b0 + q * 4 + 2 * vp) * 512 + cc] = x2[vp][tt].x;
                out[(size_t)(b0 + q * 4 + 2 * vp + 1) * 512 + cc] = x2[vp][tt].y;
            }
}

// ---------------------------------------------------------------------------
extern "C" void kernel_launch(void* const* d_in, const int* in_sizes, int n_in,
                              void* d_out, int out_size, void* d_ws, size_t ws_size,
                              hipStream_t stream) {
    const float* X  = (const float*)d_in[0];
    const float* W1 = (const float*)d_in[1];
    const float* b1 = (const float*)d_in[2];
    const float* W2 = (const float*)d_in[3];
    const float* b2 = (const float*)d_in[4];
    const float* W3 = (const float*)d_in[5];
    const float* b3 = (const float*)d_in[6];
    const float* S  = (const float*)d_in[7];
    float* out = (float*)d_out;

    char* ws = (char*)d_ws;
    size_t off = 0;
    auto alloc = [&](size_t bytes) {
        void* p = ws + off;
        off += (bytes + 255) & ~(size_t)255;
        return p;
    };
    _Float16* Xh  = (_Float16*)alloc((size_t)BATCH * 64 * 2);
    _Float16* W1t = (_Float16*)alloc((size_t)64 * 1024 * 2);
    _Float16* W2t = (_Float16*)alloc((size_t)1024 * 1024 * 2);
    _Float16* W3t = (_Float16*)alloc((size_t)1024 * 512 * 2);
    _Float16* H1  = (_Float16*)alloc((size_t)BATCH * 1024 * 2);
    _Float16* H2  = (_Float16*)alloc((size_t)BATCH * 1024 * 2);
    float*    Zb  = (float*)alloc((size_t)BATCH * 512 * 4);
    _Float16* s1f = (_Float16*)alloc((size_t)4 * 16 * 64 * 8 * 2);
    _Float16* s2f = (_Float16*)alloc((size_t)4 * 8 * 2 * 64 * 8 * 2);
    float*    tau = (float*)alloc(256);

    hipLaunchKernelGGL(prep, dim3(2369), dim3(256), 0, stream,
                       X, Xh, W1, W1t, W2, W2t, W3, W3t, S, s1f, s2f, tau);
    hipLaunchKernelGGL(gemm_relu, dim3(16, 16), dim3(256), 0, stream,
                       Xh, W1t, b1, H1, (float*)nullptr, 1024, 64);
    hipLaunchKernelGGL(gemm_relu, dim3(16, 16), dim3(256), 0, stream,
                       H1, W2t, b2, H2, (float*)nullptr, 1024, 1024);
    hipLaunchKernelGGL(gemm_relu, dim3(8, 16), dim3(256), 0, stream,
                       H2, W3t, b3, (_Float16*)nullptr, Zb, 512, 1024);
    hipLaunchKernelGGL(pdhg_mfma, dim3(BATCH / 8), dim3(512), 0, stream,
                       Zb, X, s1f, s2f, tau, out);
}

// Round 12
// 337.211 us; speedup vs baseline: 1.1279x; 1.1279x over previous
//
#include <hip/hip_runtime.h>

// ---------------------------------------------------------------------------
// MatchNet: 3-layer MLP (relu after every layer) -> batched PDHG LP solve.
// Shapes: X[2048,64], W1[64,1024], W2[1024,1024], W3[1024,512], S[64,512].
// Output: x [2048,512] fp32.
//
// R12 (= R11 with sum64 fix): ds_swizzle BitMode is 32-lane (5-bit masks);
// "xor32" 0x801F was invalid and corrupted tau. Cross-half now via shfl_xor.
// (a) pdhg norm-reduce via DPP (VALU pipe). (b) 3 barriers/iter: both waves
// of a pair hold full s1[16], redundant Kx/y_lo. (c) rsqrtf prox scale.
// ---------------------------------------------------------------------------

typedef _Float16 half8 __attribute__((ext_vector_type(8)));
typedef __fp16 fp16x2 __attribute__((ext_vector_type(2)));
typedef __fp16 fp16x4 __attribute__((ext_vector_type(4)));
typedef float floatx4 __attribute__((ext_vector_type(4)));
typedef float floatx2 __attribute__((ext_vector_type(2)));

#define BATCH 2048
#define NITERS 60
#define XBS 520   // delta-xbar LDS row stride in halves
#define YLS 72    // delta-ylo  LDS row stride in halves

typedef const __attribute__((address_space(1))) unsigned int* gptr_as1;
typedef __attribute__((address_space(3))) unsigned int* lptr_as3;
__device__ __forceinline__ void gl_lds16(const _Float16* g, _Float16* s) {
    __builtin_amdgcn_global_load_lds((gptr_as1)g, (lptr_as3)s, 16, 0, 0);
}
__device__ __forceinline__ floatx2 pmax0(floatx2 a) {
    return __builtin_elementwise_max(a, floatx2{0.f, 0.f});
}

// ---- cross-lane sums: DPP (VALU pipe) within 16-lane rows ----
template <int CTRL>
__device__ __forceinline__ float dpp_addf(float x) {
    int y = __builtin_amdgcn_update_dpp(0, __builtin_bit_cast(int, x), CTRL, 0xf, 0xf, true);
    return x + __builtin_bit_cast(float, y);
}
__device__ __forceinline__ float sum16(float x) {
    x = dpp_addf<0xB1>(x);    // quad_perm(1,0,3,2): xor 1
    x = dpp_addf<0x4E>(x);    // quad_perm(2,3,0,1): xor 2
    x = dpp_addf<0x124>(x);   // row_ror:4
    x = dpp_addf<0x128>(x);   // row_ror:8 -> full 16-lane sum in all lanes
    return x;
}
__device__ __forceinline__ float sum64(float x) {
    x = sum16(x);
    // xor16 within each 32-lane half (BitMode, 5-bit masks -> max xor 16)
    x += __builtin_bit_cast(float, __builtin_amdgcn_ds_swizzle(__builtin_bit_cast(int, x), 0x401F));
    x += __shfl_xor(x, 32, 64);   // cross-half combine
    return x;
}

// ---------------- power iteration for tau, 256-thread variant ------------------
__device__ void power_256(const float* __restrict__ S, float* __restrict__ tau_g) {
    __shared__ float vv[512], ww[64], redp[4];
    int t = threadIdx.x, wv = t >> 6, ln = t & 63;
    unsigned long long rm0 = 0, rm1 = 0, cm0 = 0, cm1 = 0;
    for (int rr = 0; rr < 8; rr++)
        for (int e = 0; e < 8; e++) {
            if (S[(wv * 16 + rr) * 512 + e * 64 + ln] != 0.f) rm0 |= 1ull << (rr * 8 + e);
            if (S[(wv * 16 + 8 + rr) * 512 + e * 64 + ln] != 0.f) rm1 |= 1ull << (rr * 8 + e);
        }
    for (int j = 0; j < 64; j++) {
        if (S[j * 512 + t] != 0.f) cm0 |= 1ull << j;
        if (S[j * 512 + t + 256] != 0.f) cm1 |= 1ull << j;
    }
    vv[t] = 0.044194173824159216f;        // 1/sqrt(512)
    vv[t + 256] = 0.044194173824159216f;
    __syncthreads();
    for (int s = 0; s <= 30; s++) {
        float ve[8];
#pragma unroll
        for (int e = 0; e < 8; e++) ve[e] = vv[e * 64 + ln];
        float pr[16];
#pragma unroll
        for (int rr = 0; rr < 8; rr++) {
            unsigned int b0 = (unsigned int)(rm0 >> (rr * 8)) & 0xffu;
            unsigned int b1 = (unsigned int)(rm1 >> (rr * 8)) & 0xffu;
            float a0 = 0.f, a1 = 0.f;
#pragma unroll
            for (int e = 0; e < 8; e++) {
                a0 += (b0 >> e & 1) ? ve[e] : 0.f;
                a1 += (b1 >> e & 1) ? ve[e] : 0.f;
            }
            pr[rr] = a0; pr[8 + rr] = a1;
        }
#pragma unroll
        for (int rr = 0; rr < 16; rr++) pr[rr] = sum64(pr[rr]);
        if (ln < 16) ww[wv * 16 + ln] = pr[ln];
        __syncthreads();
        float u0 = vv[t], u1 = vv[t + 256];
#pragma unroll
        for (int j = 0; j < 64; j++) {
            u0 += (cm0 >> j & 1) ? ww[j] : 0.f;
            u1 += (cm1 >> j & 1) ? ww[j] : 0.f;
        }
        float n2 = (s == 30) ? (vv[t] * u0 + vv[t + 256] * u1) : (u0 * u0 + u1 * u1);
        n2 = sum64(n2);
        if (ln == 0) redp[wv] = n2;
        __syncthreads();
        float tot = (redp[0] + redp[1]) + (redp[2] + redp[3]);
        if (s == 30) {
            if (t == 0) tau_g[0] = 0.9f / sqrtf(tot);
            return;
        }
        float sq = sqrtf(tot);
        vv[t] = u0 / sq;
        vv[t + 256] = u1 / sq;
        __syncthreads();
    }
}

// ---------------- merged prep: power (blk 0), cast X, W transposes, S frags ----
__global__ __launch_bounds__(256) void prep(
    const float* __restrict__ X, _Float16* __restrict__ Xh,
    const float* __restrict__ W1, _Float16* __restrict__ W1t,
    const float* __restrict__ W2, _Float16* __restrict__ W2t,
    const float* __restrict__ W3, _Float16* __restrict__ W3t,
    const float* __restrict__ S, _Float16* __restrict__ s1f,
    _Float16* __restrict__ s2f, float* __restrict__ tau_g) {
    __shared__ float tile[32][33];
    int tid = threadIdx.x;
    int bid = blockIdx.x;
    if (bid == 0) { power_256(S, tau_g); return; }
    bid -= 1;
    if (bid < 512) {
        int i = bid * 256 + tid;
        Xh[i] = (_Float16)X[i];
        return;
    }
    bid -= 512;
    if (bid < 1600) {   // transpose+cast W[K][N] -> Wt[N][K]
        const float* W; _Float16* Wt; int K, N, b;
        if (bid < 64)        { W = W1; Wt = W1t; K = 64;   N = 1024; b = bid; }
        else if (bid < 1088) { W = W2; Wt = W2t; K = 1024; N = 1024; b = bid - 64; }
        else                 { W = W3; Wt = W3t; K = 1024; N = 512;  b = bid - 1088; }
        int nbx = N / 32;
        int n0 = (b % nbx) * 32, k0 = (b / nbx) * 32;
        int tx = tid & 31, ty = tid >> 5;
#pragma unroll
        for (int i = 0; i < 4; i++)
            tile[ty + i * 8][tx] = W[(size_t)(k0 + ty + i * 8) * N + n0 + tx];
        __syncthreads();
#pragma unroll
        for (int i = 0; i < 4; i++)
            Wt[(size_t)(n0 + ty + i * 8) * K + k0 + tx] = (_Float16)tile[tx][ty + i * 8];
        return;
    }
    bid -= 1600;
    int i = bid * 256 + tid;       // 0 .. 65535
    if (i < 4 * 16 * 64 * 8) {     // s1f: B-frag of S^T, k-axis in pi-order
        int j = i & 7, lane = (i >> 3) & 63, kk = (i >> 9) & 15, wc = i >> 13;
        int p = kk * 32 + (lane >> 4) * 8 + j;
        int lmc = (p & 127) >> 3, tc = p & 7;
        int c = (p >> 7) * 128 + tc * 16 + lmc;       // pi^-1
        int m = wc * 16 + (lane & 15);
        s1f[i] = (_Float16)S[m * 512 + c];
    } else {                       // s2f: B-frag of S (k = combos)
        int i2 = i - 4 * 16 * 64 * 8;
        int j = i2 & 7, lane = (i2 >> 3) & 63, c = (i2 >> 9) & 1,
            tt = (i2 >> 10) & 7, wc = i2 >> 13;
        int kc = c * 32 + (lane >> 4) * 8 + j;
        int n = wc * 128 + tt * 16 + (lane & 15);
        s2f[i2] = (_Float16)S[kc * 512 + n];
    }
}

// ---------------- GEMM: out = relu(A[M,K] @ W[K,N] + bias), f16 in, fp32 acc ---
__global__ __launch_bounds__(256) void gemm_relu(
    const _Float16* __restrict__ A, const _Float16* __restrict__ Wt,
    const float* __restrict__ bias, _Float16* __restrict__ outh,
    float* __restrict__ outf, int N, int K) {
    __shared__ __align__(16) _Float16 As[128 * 32];
    __shared__ __align__(16) _Float16 Bs[64 * 32];
    int tid = threadIdx.x;
    int bm = blockIdx.y * 128;
    int bn = blockIdx.x * 64;
    int w = tid >> 6, l = tid & 63;
    int wr = w >> 1, wc = w & 1;
    int lm = l & 15, q = l >> 4;
    floatx4 acc[4][2] = {};

    int sr = l >> 2;
    int sc = (l & 3) * 8;
    const _Float16* ag0 = A + (size_t)(bm + w * 32 + sr) * K + sc;
    const _Float16* ag1 = A + (size_t)(bm + w * 32 + 16 + sr) * K + sc;
    _Float16* as0 = &As[(w * 32) * 32];
    _Float16* as1 = &As[(w * 32 + 16) * 32];
    const _Float16* bg = Wt + (size_t)(bn + w * 16 + sr) * K + sc;
    _Float16* bs = &Bs[(w * 16) * 32];

    for (int k0 = 0; k0 < K; k0 += 32) {
        gl_lds16(ag0 + k0, as0);
        gl_lds16(ag1 + k0, as1);
        gl_lds16(bg + k0, bs);
        __syncthreads();
        half8 af[4], bf[2];
#pragma unroll
        for (int mt = 0; mt < 4; mt++)
            af[mt] = *(const half8*)&As[(wr * 64 + mt * 16 + lm) * 32 + q * 8];
#pragma unroll
        for (int nt = 0; nt < 2; nt++)
            bf[nt] = *(const half8*)&Bs[(wc * 32 + nt * 16 + lm) * 32 + q * 8];
#pragma unroll
        for (int mt = 0; mt < 4; mt++)
#pragma unroll
            for (int nt = 0; nt < 2; nt++)
                acc[mt][nt] = __builtin_amdgcn_mfma_f32_16x16x32_f16(
                    af[mt], bf[nt], acc[mt][nt], 0, 0, 0);
        __syncthreads();
    }
#pragma unroll
    for (int nt = 0; nt < 2; nt++) {
        int col = bn + wc * 32 + nt * 16 + lm;
        float bv = bias[col];
#pragma unroll
        for (int mt = 0; mt < 4; mt++) {
#pragma unroll
            for (int v = 0; v < 4; v++) {
                int row = bm + wr * 64 + mt * 16 + q * 4 + v;
                float val = fmaxf(acc[mt][nt][v] + bv, 0.f);
                if (outh) outh[(size_t)row * N + col] = (_Float16)val;
                else      outf[(size_t)row * N + col] = val;
            }
        }
    }
}

// ---------------- Delta-form MFMA PDHG, 8 waves, 3 barriers, 60 iterations -----
// Block = 8 batch rows, 512 threads = 8 waves (2/SIMD). Pair p = wave>>1 owns
// combos [p*16,+16) and cols [p*128,+128). Both waves of a pair hold the full
// s1[16] and redundantly compute Kx + y_lo (bitwise-identical); sub s = wave&1
// owns KTy t-tiles [s*4,+4) and publishes yl rows vp==s. Norm reduce via DPP.
__global__ __launch_bounds__(512, 2) void pdhg_mfma(
    const float* __restrict__ Zb, const float* __restrict__ Xf,
    const _Float16* __restrict__ s1f, const _Float16* __restrict__ s2f,
    const float* __restrict__ tau_p, float* __restrict__ out) {
    __shared__ __align__(16) _Float16 xb_d[16 * XBS];
    __shared__ __align__(16) _Float16 yl_d[16 * YLS];
    __shared__ __align__(16) float red[16][8];
    int tid = threadIdx.x;
    int wave = tid >> 6, p = wave >> 1, s = wave & 1;
    int l = tid & 63, lm = l & 15, q = l >> 4;
    int b0 = blockIdx.x * 8;
    bool act = (q < 2);

    // constant S fragments: full Kx set + this sub's KTy tiles
    half8 s1[16], s2[4][2];
#pragma unroll
    for (int k = 0; k < 16; k++)
        s1[k] = *(const half8*)&s1f[((p * 16 + k) * 64 + l) * 8];
#pragma unroll
    for (int tt = 0; tt < 4; tt++)
#pragma unroll
        for (int c = 0; c < 2; c++)
            s2[tt][c] = *(const half8*)&s2f[(((p * 8 + s * 4 + tt) * 2 + c) * 64 + l) * 8];

    // paired state over this sub's 64 cols: [vp][tt], rows v = 2vp+c
    floatx2 z2[2][4], x2[2][4], xb2[2][4], yh2[2][4], d2[2][4];
    floatx2 ylo2[2], Bc2[2];
    floatx4 a1p[4] = {};            // running S.xbar (full, duplicated per sub)
    floatx4 acc2[4] = {};           // running S^T.ylo (this sub's t-tiles)
    float tau = tau_p[0];
    float sig = tau;
#pragma unroll
    for (int vp = 0; vp < 2; vp++) {
        int r0 = b0 + ((q * 4 + 2 * vp) & 7);
        int r1 = b0 + ((q * 4 + 2 * vp + 1) & 7);
        Bc2[vp] = floatx2{Xf[r0 * 64 + p * 16 + lm], Xf[r1 * 64 + p * 16 + lm]};
        ylo2[vp] = floatx2{0.f, 0.f};
#pragma unroll
        for (int tt = 0; tt < 4; tt++) {
            int cc = p * 128 + (s * 4 + tt) * 16 + lm;
            z2[vp][tt] = floatx2{Zb[(size_t)r0 * 512 + cc], Zb[(size_t)r1 * 512 + cc]};
            x2[vp][tt] = floatx2{0.f, 0.f};
            xb2[vp][tt] = floatx2{0.f, 0.f};
            yh2[vp][tt] = floatx2{0.f, 0.f};
        }
    }
    {
        half8 hz = {0, 0, 0, 0, 0, 0, 0, 0};
        for (int i = tid; i < (16 * XBS) / 8; i += 512)
            *(half8*)&xb_d[i * 8] = hz;
        for (int i = tid; i < 16 * YLS; i += 512)
            yl_d[i] = (_Float16)0.f;
    }
    __syncthreads();

#pragma unroll 1
    for (int it = 0; it < NITERS; ++it) {
        // ---- Kx increment: full 16 chunks (both subs, identical) ----
#pragma unroll
        for (int k = 0; k < 16; k++) {
            half8 ad = *(const half8*)&xb_d[lm * XBS + k * 32 + q * 8];
            a1p[k & 3] = __builtin_amdgcn_mfma_f32_16x16x32_f16(ad, s1[k], a1p[k & 3], 0, 0, 0);
        }
        floatx4 a1 = (a1p[0] + a1p[1]) + (a1p[2] + a1p[3]);
        // ---- y_lo update (both subs); sub s publishes rows vp == s ----
#pragma unroll
        for (int vp = 0; vp < 2; vp++) {
            floatx2 av = (vp == 0) ? floatx2{a1.x, a1.y} : floatx2{a1.z, a1.w};
            floatx2 yv = pmax0(ylo2[vp] + sig * (av - Bc2[vp]));
            floatx2 dy = yv - ylo2[vp];
            ylo2[vp] = yv;
            if (act && vp == s) {
                fp16x2 pk = __builtin_amdgcn_cvt_pkrtz(dy.x, dy.y);
                int a0 = (q * 4 + 2 * vp) * YLS + p * 16 + lm;
                yl_d[a0] = (_Float16)pk[0];
                yl_d[a0 + YLS] = (_Float16)pk[1];
            }
        }
        __syncthreads();   // [A] delta-y plane ready
        // ---- KTy increment: acc2 += d_y @ S (this sub's 4 t-tiles) ----
        half8 a2d[2];
#pragma unroll
        for (int c = 0; c < 2; c++)
            a2d[c] = *(const half8*)&yl_d[lm * YLS + c * 32 + q * 8];
#pragma unroll
        for (int tt = 0; tt < 4; tt++)
#pragma unroll
            for (int c = 0; c < 2; c++)
                acc2[tt] = __builtin_amdgcn_mfma_f32_16x16x32_f16(a2d[c], s2[tt][c], acc2[tt], 0, 0, 0);
        // ---- packed: y_hi update, d = (x - tau*kty) + (tau - z), norm partials ----
        floatx2 pn2[2] = {floatx2{0.f, 0.f}, floatx2{0.f, 0.f}};
#pragma unroll
        for (int vp = 0; vp < 2; vp++)
#pragma unroll
            for (int tt = 0; tt < 4; tt++) {
                floatx2 accp = (vp == 0) ? floatx2{acc2[tt].x, acc2[tt].y}
                                         : floatx2{acc2[tt].z, acc2[tt].w};
                yh2[vp][tt] = pmax0(yh2[vp][tt] - sig * xb2[vp][tt]);
                floatx2 kty = accp - yh2[vp][tt];
                floatx2 dd = (x2[vp][tt] - tau * kty) + (tau - z2[vp][tt]);
                d2[vp][tt] = dd;
                pn2[vp] += dd * dd;
            }
        float pn[4] = {pn2[0].x, pn2[0].y, pn2[1].x, pn2[1].y};
#pragma unroll
        for (int v = 0; v < 4; v++) pn[v] = sum16(pn[v]);   // DPP, VALU-pipe
        if (lm == 0)
#pragma unroll
            for (int v = 0; v < 4; v++) red[q * 4 + v][wave] = pn[v];
        __syncthreads();   // [B] norm partials ready
        floatx2 sc2[2];
#pragma unroll
        for (int vp = 0; vp < 2; vp++)
#pragma unroll
            for (int c = 0; c < 2; c++) {
                int v = 2 * vp + c;
                floatx4 r0 = *(const floatx4*)&red[q * 4 + v][0];
                floatx4 r1 = *(const floatx4*)&red[q * 4 + v][4];
                floatx4 rr = r0 + r1;
                float n2 = (rr.x + rr.y) + (rr.z + rr.w);
                float sv = fmaxf(1.f - tau * rsqrtf(fmaxf(n2, 1e-24f)), 0.f);
                if (c == 0) sc2[vp].x = sv; else sc2[vp].y = sv;
            }
        // ---- packed prox + delta-xbar publish (pi-order: fp16x4 per v) ----
#pragma unroll
        for (int vp = 0; vp < 2; vp++) {
#pragma unroll
            for (int tt = 0; tt < 4; tt++) {
                floatx2 xn = z2[vp][tt] + sc2[vp] * d2[vp][tt];
                floatx2 xbn = 2.f * xn - x2[vp][tt];
                d2[vp][tt] = xbn - xb2[vp][tt];   // reuse d2 as delta
                x2[vp][tt] = xn;
                xb2[vp][tt] = xbn;
            }
            if (act) {
#pragma unroll
                for (int c = 0; c < 2; c++) {
                    fp16x2 p0 = __builtin_amdgcn_cvt_pkrtz(
                        (c == 0) ? d2[vp][0].x : d2[vp][0].y,
                        (c == 0) ? d2[vp][1].x : d2[vp][1].y);
                    fp16x2 p1 = __builtin_amdgcn_cvt_pkrtz(
                        (c == 0) ? d2[vp][2].x : d2[vp][2].y,
                        (c == 0) ? d2[vp][3].x : d2[vp][3].y);
                    fp16x4 hd = __builtin_shufflevector(p0, p1, 0, 1, 2, 3);
                    int v = 2 * vp + c;
                    *(fp16x4*)&xb_d[(q * 4 + v) * XBS + p * 128 + lm * 8 + s * 4] = hd;
                }
            }
        }
        __syncthreads();   // [C] delta-xbar plane ready for next iteration
    }
    if (act)
#pragma unroll
        for (int vp = 0; vp < 2; vp++)
#pragma unroll
            for (int tt = 0; tt < 4; tt++) {
                int cc = p * 128 + (s * 4 + tt) * 16 + lm;
                out[(size_t)(b0 + q * 4 + 2 * vp) * 512 + cc] = x2[vp][tt].x;
                out[(size_t)(b0 + q * 4 + 2 * vp + 1) * 512 + cc] = x2[vp][tt].y;
            }
}

// ---------------------------------------------------------------------------
extern "C" void kernel_launch(void* const* d_in, const int* in_sizes, int n_in,
                              void* d_out, int out_size, void* d_ws, size_t ws_size,
                              hipStream_t stream) {
    const float* X  = (const float*)d_in[0];
    const float* W1 = (const float*)d_in[1];
    const float* b1 = (const float*)d_in[2];
    const float* W2 = (const float*)d_in[3];
    const float* b2 = (const float*)d_in[4];
    const float* W3 = (const float*)d_in[5];
    const float* b3 = (const float*)d_in[6];
    const float* S  = (const float*)d_in[7];
    float* out = (float*)d_out;

    char* ws = (char*)d_ws;
    size_t off = 0;
    auto alloc = [&](size_t bytes) {
        void* p = ws + off;
        off += (bytes + 255) & ~(size_t)255;
        return p;
    };
    _Float16* Xh  = (_Float16*)alloc((size_t)BATCH * 64 * 2);
    _Float16* W1t = (_Float16*)alloc((size_t)64 * 1024 * 2);
    _Float16* W2t = (_Float16*)alloc((size_t)1024 * 1024 * 2);
    _Float16* W3t = (_Float16*)alloc((size_t)1024 * 512 * 2);
    _Float16* H1  = (_Float16*)alloc((size_t)BATCH * 1024 * 2);
    _Float16* H2  = (_Float16*)alloc((size_t)BATCH * 1024 * 2);
    float*    Zb  = (float*)alloc((size_t)BATCH * 512 * 4);
    _Float16* s1f = (_Float16*)alloc((size_t)4 * 16 * 64 * 8 * 2);
    _Float16* s2f = (_Float16*)alloc((size_t)4 * 8 * 2 * 64 * 8 * 2);
    float*    tau = (float*)alloc(256);

    hipLaunchKernelGGL(prep, dim3(2369), dim3(256), 0, stream,
                       X, Xh, W1, W1t, W2, W2t, W3, W3t, S, s1f, s2f, tau);
    hipLaunchKernelGGL(gemm_relu, dim3(16, 16), dim3(256), 0, stream,
                       Xh, W1t, b1, H1, (float*)nullptr, 1024, 64);
    hipLaunchKernelGGL(gemm_relu, dim3(16, 16), dim3(256), 0, stream,
                       H1, W2t, b2, H2, (float*)nullptr, 1024, 1024);
    hipLaunchKernelGGL(gemm_relu, dim3(8, 16), dim3(256), 0, stream,
                       H2, W3t, b3, (_Float16*)nullptr, Zb, 512, 1024);
    hipLaunchKernelGGL(pdhg_mfma, dim3(BATCH / 8), dim3(512), 0, stream,
                       Zb, X, s1f, s2f, tau, out);
}

// Round 13
// 336.697 us; speedup vs baseline: 1.1296x; 1.0015x over previous
//
#include <hip/hip_runtime.h>

// ---------------------------------------------------------------------------
// MatchNet: 3-layer MLP (relu after every layer) -> batched PDHG LP solve.
// Shapes: X[2048,64], W1[64,1024], W2[1024,1024], W3[1024,512], S[64,512].
// Output: x [2048,512] fp32.
//
// R13: power_256 de-latency-chained. R12 evidence: prep ran 122.7 us at
// VALUBusy 0.5% / occ 1.1% / VGPR 28 -> single straggler block (power) stuck
// in a 64-deep ds_read->cndmask->add chain per step. Fix: ww preloaded into
// 16 float4 registers (same accumulation order -> bit-identical tau), and
// mask-build global loads explicitly batched. pdhg frozen at R12 (122.5 us).
// ---------------------------------------------------------------------------

typedef _Float16 half8 __attribute__((ext_vector_type(8)));
typedef __fp16 fp16x2 __attribute__((ext_vector_type(2)));
typedef __fp16 fp16x4 __attribute__((ext_vector_type(4)));
typedef float floatx4 __attribute__((ext_vector_type(4)));
typedef float floatx2 __attribute__((ext_vector_type(2)));

#define BATCH 2048
#define NITERS 60
#define XBS 520   // delta-xbar LDS row stride in halves
#define YLS 72    // delta-ylo  LDS row stride in halves

typedef const __attribute__((address_space(1))) unsigned int* gptr_as1;
typedef __attribute__((address_space(3))) unsigned int* lptr_as3;
__device__ __forceinline__ void gl_lds16(const _Float16* g, _Float16* s) {
    __builtin_amdgcn_global_load_lds((gptr_as1)g, (lptr_as3)s, 16, 0, 0);
}
__device__ __forceinline__ floatx2 pmax0(floatx2 a) {
    return __builtin_elementwise_max(a, floatx2{0.f, 0.f});
}

// ---- cross-lane sums: DPP (VALU pipe) within 16-lane rows ----
template <int CTRL>
__device__ __forceinline__ float dpp_addf(float x) {
    int y = __builtin_amdgcn_update_dpp(0, __builtin_bit_cast(int, x), CTRL, 0xf, 0xf, true);
    return x + __builtin_bit_cast(float, y);
}
__device__ __forceinline__ float sum16(float x) {
    x = dpp_addf<0xB1>(x);    // quad_perm(1,0,3,2): xor 1
    x = dpp_addf<0x4E>(x);    // quad_perm(2,3,0,1): xor 2
    x = dpp_addf<0x124>(x);   // row_ror:4
    x = dpp_addf<0x128>(x);   // row_ror:8 -> full 16-lane sum in all lanes
    return x;
}
__device__ __forceinline__ float sum64(float x) {
    x = sum16(x);
    // xor16 within each 32-lane half (BitMode, 5-bit masks -> max xor 16)
    x += __builtin_bit_cast(float, __builtin_amdgcn_ds_swizzle(__builtin_bit_cast(int, x), 0x401F));
    x += __shfl_xor(x, 32, 64);   // cross-half combine
    return x;
}

// ---------------- power iteration for tau, 256-thread variant ------------------
__device__ void power_256(const float* __restrict__ S, float* __restrict__ tau_g) {
    __shared__ float vv[512], ww[64], redp[4];
    int t = threadIdx.x, wv = t >> 6, ln = t & 63;
    // ---- mask build, batched loads (>=16 in flight) ----
    unsigned long long rm0 = 0, rm1 = 0, cm0 = 0, cm1 = 0;
    for (int rr = 0; rr < 8; rr++) {
        float v0[8], v1[8];
#pragma unroll
        for (int e = 0; e < 8; e++) {
            v0[e] = S[(wv * 16 + rr) * 512 + e * 64 + ln];
            v1[e] = S[(wv * 16 + 8 + rr) * 512 + e * 64 + ln];
        }
#pragma unroll
        for (int e = 0; e < 8; e++) {
            if (v0[e] != 0.f) rm0 |= 1ull << (rr * 8 + e);
            if (v1[e] != 0.f) rm1 |= 1ull << (rr * 8 + e);
        }
    }
    for (int jb = 0; jb < 4; jb++) {
        float c0[16], c1[16];
#pragma unroll
        for (int jj = 0; jj < 16; jj++) {
            c0[jj] = S[(jb * 16 + jj) * 512 + t];
            c1[jj] = S[(jb * 16 + jj) * 512 + t + 256];
        }
#pragma unroll
        for (int jj = 0; jj < 16; jj++) {
            if (c0[jj] != 0.f) cm0 |= 1ull << (jb * 16 + jj);
            if (c1[jj] != 0.f) cm1 |= 1ull << (jb * 16 + jj);
        }
    }
    vv[t] = 0.044194173824159216f;        // 1/sqrt(512)
    vv[t + 256] = 0.044194173824159216f;
    __syncthreads();
    for (int s = 0; s <= 30; s++) {
        float ve[8];
#pragma unroll
        for (int e = 0; e < 8; e++) ve[e] = vv[e * 64 + ln];
        float pr[16];
#pragma unroll
        for (int rr = 0; rr < 8; rr++) {
            unsigned int b0 = (unsigned int)(rm0 >> (rr * 8)) & 0xffu;
            unsigned int b1 = (unsigned int)(rm1 >> (rr * 8)) & 0xffu;
            float a0 = 0.f, a1 = 0.f;
#pragma unroll
            for (int e = 0; e < 8; e++) {
                a0 += (b0 >> e & 1) ? ve[e] : 0.f;
                a1 += (b1 >> e & 1) ? ve[e] : 0.f;
            }
            pr[rr] = a0; pr[8 + rr] = a1;
        }
#pragma unroll
        for (int rr = 0; rr < 16; rr++) pr[rr] = sum64(pr[rr]);
        if (ln < 16) ww[wv * 16 + ln] = pr[ln];
        __syncthreads();
        // ---- ww -> registers (16 independent b128 reads), then VALU-only sum.
        // Accumulation order over j is unchanged -> tau bit-identical.
        floatx4 w4[16];
#pragma unroll
        for (int jj = 0; jj < 16; jj++) w4[jj] = *(const floatx4*)&ww[jj * 4];
        float u0 = vv[t], u1 = vv[t + 256];
#pragma unroll
        for (int j = 0; j < 64; j++) {
            float wj = w4[j >> 2][j & 3];
            u0 += (cm0 >> j & 1) ? wj : 0.f;
            u1 += (cm1 >> j & 1) ? wj : 0.f;
        }
        float n2 = (s == 30) ? (vv[t] * u0 + vv[t + 256] * u1) : (u0 * u0 + u1 * u1);
        n2 = sum64(n2);
        if (ln == 0) redp[wv] = n2;
        __syncthreads();
        float tot = (redp[0] + redp[1]) + (redp[2] + redp[3]);
        if (s == 30) {
            if (t == 0) tau_g[0] = 0.9f / sqrtf(tot);
            return;
        }
        float sq = sqrtf(tot);
        vv[t] = u0 / sq;
        vv[t + 256] = u1 / sq;
        __syncthreads();
    }
}

// ---------------- merged prep: power (blk 0), cast X, W transposes, S frags ----
__global__ __launch_bounds__(256) void prep(
    const float* __restrict__ X, _Float16* __restrict__ Xh,
    const float* __restrict__ W1, _Float16* __restrict__ W1t,
    const float* __restrict__ W2, _Float16* __restrict__ W2t,
    const float* __restrict__ W3, _Float16* __restrict__ W3t,
    const float* __restrict__ S, _Float16* __restrict__ s1f,
    _Float16* __restrict__ s2f, float* __restrict__ tau_g) {
    __shared__ float tile[32][33];
    int tid = threadIdx.x;
    int bid = blockIdx.x;
    if (bid == 0) { power_256(S, tau_g); return; }
    bid -= 1;
    if (bid < 512) {
        int i = bid * 256 + tid;
        Xh[i] = (_Float16)X[i];
        return;
    }
    bid -= 512;
    if (bid < 1600) {   // transpose+cast W[K][N] -> Wt[N][K]
        const float* W; _Float16* Wt; int K, N, b;
        if (bid < 64)        { W = W1; Wt = W1t; K = 64;   N = 1024; b = bid; }
        else if (bid < 1088) { W = W2; Wt = W2t; K = 1024; N = 1024; b = bid - 64; }
        else                 { W = W3; Wt = W3t; K = 1024; N = 512;  b = bid - 1088; }
        int nbx = N / 32;
        int n0 = (b % nbx) * 32, k0 = (b / nbx) * 32;
        int tx = tid & 31, ty = tid >> 5;
#pragma unroll
        for (int i = 0; i < 4; i++)
            tile[ty + i * 8][tx] = W[(size_t)(k0 + ty + i * 8) * N + n0 + tx];
        __syncthreads();
#pragma unroll
        for (int i = 0; i < 4; i++)
            Wt[(size_t)(n0 + ty + i * 8) * K + k0 + tx] = (_Float16)tile[tx][ty + i * 8];
        return;
    }
    bid -= 1600;
    int i = bid * 256 + tid;       // 0 .. 65535
    if (i < 4 * 16 * 64 * 8) {     // s1f: B-frag of S^T, k-axis in pi-order
        int j = i & 7, lane = (i >> 3) & 63, kk = (i >> 9) & 15, wc = i >> 13;
        int p = kk * 32 + (lane >> 4) * 8 + j;
        int lmc = (p & 127) >> 3, tc = p & 7;
        int c = (p >> 7) * 128 + tc * 16 + lmc;       // pi^-1
        int m = wc * 16 + (lane & 15);
        s1f[i] = (_Float16)S[m * 512 + c];
    } else {                       // s2f: B-frag of S (k = combos)
        int i2 = i - 4 * 16 * 64 * 8;
        int j = i2 & 7, lane = (i2 >> 3) & 63, c = (i2 >> 9) & 1,
            tt = (i2 >> 10) & 7, wc = i2 >> 13;
        int kc = c * 32 + (lane >> 4) * 8 + j;
        int n = wc * 128 + tt * 16 + (lane & 15);
        s2f[i2] = (_Float16)S[kc * 512 + n];
    }
}

// ---------------- GEMM: out = relu(A[M,K] @ W[K,N] + bias), f16 in, fp32 acc ---
__global__ __launch_bounds__(256) void gemm_relu(
    const _Float16* __restrict__ A, const _Float16* __restrict__ Wt,
    const float* __restrict__ bias, _Float16* __restrict__ outh,
    float* __restrict__ outf, int N, int K) {
    __shared__ __align__(16) _Float16 As[128 * 32];
    __shared__ __align__(16) _Float16 Bs[64 * 32];
    int tid = threadIdx.x;
    int bm = blockIdx.y * 128;
    int bn = blockIdx.x * 64;
    int w = tid >> 6, l = tid & 63;
    int wr = w >> 1, wc = w & 1;
    int lm = l & 15, q = l >> 4;
    floatx4 acc[4][2] = {};

    int sr = l >> 2;
    int sc = (l & 3) * 8;
    const _Float16* ag0 = A + (size_t)(bm + w * 32 + sr) * K + sc;
    const _Float16* ag1 = A + (size_t)(bm + w * 32 + 16 + sr) * K + sc;
    _Float16* as0 = &As[(w * 32) * 32];
    _Float16* as1 = &As[(w * 32 + 16) * 32];
    const _Float16* bg = Wt + (size_t)(bn + w * 16 + sr) * K + sc;
    _Float16* bs = &Bs[(w * 16) * 32];

    for (int k0 = 0; k0 < K; k0 += 32) {
        gl_lds16(ag0 + k0, as0);
        gl_lds16(ag1 + k0, as1);
        gl_lds16(bg + k0, bs);
        __syncthreads();
        half8 af[4], bf[2];
#pragma unroll
        for (int mt = 0; mt < 4; mt++)
            af[mt] = *(const half8*)&As[(wr * 64 + mt * 16 + lm) * 32 + q * 8];
#pragma unroll
        for (int nt = 0; nt < 2; nt++)
            bf[nt] = *(const half8*)&Bs[(wc * 32 + nt * 16 + lm) * 32 + q * 8];
#pragma unroll
        for (int mt = 0; mt < 4; mt++)
#pragma unroll
            for (int nt = 0; nt < 2; nt++)
                acc[mt][nt] = __builtin_amdgcn_mfma_f32_16x16x32_f16(
                    af[mt], bf[nt], acc[mt][nt], 0, 0, 0);
        __syncthreads();
    }
#pragma unroll
    for (int nt = 0; nt < 2; nt++) {
        int col = bn + wc * 32 + nt * 16 + lm;
        float bv = bias[col];
#pragma unroll
        for (int mt = 0; mt < 4; mt++) {
#pragma unroll
            for (int v = 0; v < 4; v++) {
                int row = bm + wr * 64 + mt * 16 + q * 4 + v;
                float val = fmaxf(acc[mt][nt][v] + bv, 0.f);
                if (outh) outh[(size_t)row * N + col] = (_Float16)val;
                else      outf[(size_t)row * N + col] = val;
            }
        }
    }
}

// ---------------- Delta-form MFMA PDHG, 8 waves, 3 barriers, 60 iterations -----
// Block = 8 batch rows, 512 threads = 8 waves (2/SIMD). Pair p = wave>>1 owns
// combos [p*16,+16) and cols [p*128,+128). Both waves of a pair hold the full
// s1[16] and redundantly compute Kx + y_lo (bitwise-identical); sub s = wave&1
// owns KTy t-tiles [s*4,+4) and publishes yl rows vp==s. Norm reduce via DPP.
__global__ __launch_bounds__(512, 2) void pdhg_mfma(
    const float* __restrict__ Zb, const float* __restrict__ Xf,
    const _Float16* __restrict__ s1f, const _Float16* __restrict__ s2f,
    const float* __restrict__ tau_p, float* __restrict__ out) {
    __shared__ __align__(16) _Float16 xb_d[16 * XBS];
    __shared__ __align__(16) _Float16 yl_d[16 * YLS];
    __shared__ __align__(16) float red[16][8];
    int tid = threadIdx.x;
    int wave = tid >> 6, p = wave >> 1, s = wave & 1;
    int l = tid & 63, lm = l & 15, q = l >> 4;
    int b0 = blockIdx.x * 8;
    bool act = (q < 2);

    // constant S fragments: full Kx set + this sub's KTy tiles
    half8 s1[16], s2[4][2];
#pragma unroll
    for (int k = 0; k < 16; k++)
        s1[k] = *(const half8*)&s1f[((p * 16 + k) * 64 + l) * 8];
#pragma unroll
    for (int tt = 0; tt < 4; tt++)
#pragma unroll
        for (int c = 0; c < 2; c++)
            s2[tt][c] = *(const half8*)&s2f[(((p * 8 + s * 4 + tt) * 2 + c) * 64 + l) * 8];

    // paired state over this sub's 64 cols: [vp][tt], rows v = 2vp+c
    floatx2 z2[2][4], x2[2][4], xb2[2][4], yh2[2][4], d2[2][4];
    floatx2 ylo2[2], Bc2[2];
    floatx4 a1p[4] = {};            // running S.xbar (full, duplicated per sub)
    floatx4 acc2[4] = {};           // running S^T.ylo (this sub's t-tiles)
    float tau = tau_p[0];
    float sig = tau;
#pragma unroll
    for (int vp = 0; vp < 2; vp++) {
        int r0 = b0 + ((q * 4 + 2 * vp) & 7);
        int r1 = b0 + ((q * 4 + 2 * vp + 1) & 7);
        Bc2[vp] = floatx2{Xf[r0 * 64 + p * 16 + lm], Xf[r1 * 64 + p * 16 + lm]};
        ylo2[vp] = floatx2{0.f, 0.f};
#pragma unroll
        for (int tt = 0; tt < 4; tt++) {
            int cc = p * 128 + (s * 4 + tt) * 16 + lm;
            z2[vp][tt] = floatx2{Zb[(size_t)r0 * 512 + cc], Zb[(size_t)r1 * 512 + cc]};
            x2[vp][tt] = floatx2{0.f, 0.f};
            xb2[vp][tt] = floatx2{0.f, 0.f};
            yh2[vp][tt] = floatx2{0.f, 0.f};
        }
    }
    {
        half8 hz = {0, 0, 0, 0, 0, 0, 0, 0};
        for (int i = tid; i < (16 * XBS) / 8; i += 512)
            *(half8*)&xb_d[i * 8] = hz;
        for (int i = tid; i < 16 * YLS; i += 512)
            yl_d[i] = (_Float16)0.f;
    }
    __syncthreads();

#pragma unroll 1
    for (int it = 0; it < NITERS; ++it) {
        // ---- Kx increment: full 16 chunks (both subs, identical) ----
#pragma unroll
        for (int k = 0; k < 16; k++) {
            half8 ad = *(const half8*)&xb_d[lm * XBS + k * 32 + q * 8];
            a1p[k & 3] = __builtin_amdgcn_mfma_f32_16x16x32_f16(ad, s1[k], a1p[k & 3], 0, 0, 0);
        }
        floatx4 a1 = (a1p[0] + a1p[1]) + (a1p[2] + a1p[3]);
        // ---- y_lo update (both subs); sub s publishes rows vp == s ----
#pragma unroll
        for (int vp = 0; vp < 2; vp++) {
            floatx2 av = (vp == 0) ? floatx2{a1.x, a1.y} : floatx2{a1.z, a1.w};
            floatx2 yv = pmax0(ylo2[vp] + sig * (av - Bc2[vp]));
            floatx2 dy = yv - ylo2[vp];
            ylo2[vp] = yv;
            if (act && vp == s) {
                fp16x2 pk = __builtin_amdgcn_cvt_pkrtz(dy.x, dy.y);
                int a0 = (q * 4 + 2 * vp) * YLS + p * 16 + lm;
                yl_d[a0] = (_Float16)pk[0];
                yl_d[a0 + YLS] = (_Float16)pk[1];
            }
        }
        __syncthreads();   // [A] delta-y plane ready
        // ---- KTy increment: acc2 += d_y @ S (this sub's 4 t-tiles) ----
        half8 a2d[2];
#pragma unroll
        for (int c = 0; c < 2; c++)
            a2d[c] = *(const half8*)&yl_d[lm * YLS + c * 32 + q * 8];
#pragma unroll
        for (int tt = 0; tt < 4; tt++)
#pragma unroll
            for (int c = 0; c < 2; c++)
                acc2[tt] = __builtin_amdgcn_mfma_f32_16x16x32_f16(a2d[c], s2[tt][c], acc2[tt], 0, 0, 0);
        // ---- packed: y_hi update, d = (x - tau*kty) + (tau - z), norm partials ----
        floatx2 pn2[2] = {floatx2{0.f, 0.f}, floatx2{0.f, 0.f}};
#pragma unroll
        for (int vp = 0; vp < 2; vp++)
#pragma unroll
            for (int tt = 0; tt < 4; tt++) {
                floatx2 accp = (vp == 0) ? floatx2{acc2[tt].x, acc2[tt].y}
                                         : floatx2{acc2[tt].z, acc2[tt].w};
                yh2[vp][tt] = pmax0(yh2[vp][tt] - sig * xb2[vp][tt]);
                floatx2 kty = accp - yh2[vp][tt];
                floatx2 dd = (x2[vp][tt] - tau * kty) + (tau - z2[vp][tt]);
                d2[vp][tt] = dd;
                pn2[vp] += dd * dd;
            }
        float pn[4] = {pn2[0].x, pn2[0].y, pn2[1].x, pn2[1].y};
#pragma unroll
        for (int v = 0; v < 4; v++) pn[v] = sum16(pn[v]);   // DPP, VALU-pipe
        if (lm == 0)
#pragma unroll
            for (int v = 0; v < 4; v++) red[q * 4 + v][wave] = pn[v];
        __syncthreads();   // [B] norm partials ready
        floatx2 sc2[2];
#pragma unroll
        for (int vp = 0; vp < 2; vp++)
#pragma unroll
            for (int c = 0; c < 2; c++) {
                int v = 2 * vp + c;
                floatx4 r0 = *(const floatx4*)&red[q * 4 + v][0];
                floatx4 r1 = *(const floatx4*)&red[q * 4 + v][4];
                floatx4 rr = r0 + r1;
                float n2 = (rr.x + rr.y) + (rr.z + rr.w);
                float sv = fmaxf(1.f - tau * rsqrtf(fmaxf(n2, 1e-24f)), 0.f);
                if (c == 0) sc2[vp].x = sv; else sc2[vp].y = sv;
            }
        // ---- packed prox + delta-xbar publish (pi-order: fp16x4 per v) ----
#pragma unroll
        for (int vp = 0; vp < 2; vp++) {
#pragma unroll
            for (int tt = 0; tt < 4; tt++) {
                floatx2 xn = z2[vp][tt] + sc2[vp] * d2[vp][tt];
                floatx2 xbn = 2.f * xn - x2[vp][tt];
                d2[vp][tt] = xbn - xb2[vp][tt];   // reuse d2 as delta
                x2[vp][tt] = xn;
                xb2[vp][tt] = xbn;
            }
            if (act) {
#pragma unroll
                for (int c = 0; c < 2; c++) {
                    fp16x2 p0 = __builtin_amdgcn_cvt_pkrtz(
                        (c == 0) ? d2[vp][0].x : d2[vp][0].y,
                        (c == 0) ? d2[vp][1].x : d2[vp][1].y);
                    fp16x2 p1 = __builtin_amdgcn_cvt_pkrtz(
                        (c == 0) ? d2[vp][2].x : d2[vp][2].y,
                        (c == 0) ? d2[vp][3].x : d2[vp][3].y);
                    fp16x4 hd = __builtin_shufflevector(p0, p1, 0, 1, 2, 3);
                    int v = 2 * vp + c;
                    *(fp16x4*)&xb_d[(q * 4 + v) * XBS + p * 128 + lm * 8 + s * 4] = hd;
                }
            }
        }
        __syncthreads();   // [C] delta-xbar plane ready for next iteration
    }
    if (act)
#pragma unroll
        for (int vp = 0; vp < 2; vp++)
#pragma unroll
            for (int tt = 0; tt < 4; tt++) {
                int cc = p * 128 + (s * 4 + tt) * 16 + lm;
                out[(size_t)(b0 + q * 4 + 2 * vp) * 512 + cc] = x2[vp][tt].x;
                out[(size_t)(b0 + q * 4 + 2 * vp + 1) * 512 + cc] = x2[vp][tt].y;
            }
}

// ---------------------------------------------------------------------------
extern "C" void kernel_launch(void* const* d_in, const int* in_sizes, int n_in,
                              void* d_out, int out_size, void* d_ws, size_t ws_size,
                              hipStream_t stream) {
    const float* X  = (const float*)d_in[0];
    const float* W1 = (const float*)d_in[1];
    const float* b1 = (const float*)d_in[2];
    const float* W2 = (const float*)d_in[3];
    const float* b2 = (const float*)d_in[4];
    const float* W3 = (const float*)d_in[5];
    const float* b3 = (const float*)d_in[6];
    const float* S  = (const float*)d_in[7];
    float* out = (float*)d_out;

    char* ws = (char*)d_ws;
    size_t off = 0;
    auto alloc = [&](size_t bytes) {
        void* p = ws + off;
        off += (bytes + 255) & ~(size_t)255;
        return p;
    };
    _Float16* Xh  = (_Float16*)alloc((size_t)BATCH * 64 * 2);
    _Float16* W1t = (_Float16*)alloc((size_t)64 * 1024 * 2);
    _Float16* W2t = (_Float16*)alloc((size_t)1024 * 1024 * 2);
    _Float16* W3t = (_Float16*)alloc((size_t)1024 * 512 * 2);
    _Float16* H1  = (_Float16*)alloc((size_t)BATCH * 1024 * 2);
    _Float16* H2  = (_Float16*)alloc((size_t)BATCH * 1024 * 2);
    float*    Zb  = (float*)alloc((size_t)BATCH * 512 * 4);
    _Float16* s1f = (_Float16*)alloc((size_t)4 * 16 * 64 * 8 * 2);
    _Float16* s2f = (_Float16*)alloc((size_t)4 * 8 * 2 * 64 * 8 * 2);
    float*    tau = (float*)alloc(256);

    hipLaunchKernelGGL(prep, dim3(2369), dim3(256), 0, stream,
                       X, Xh, W1, W1t, W2, W2t, W3, W3t, S, s1f, s2f, tau);
    hipLaunchKernelGGL(gemm_relu, dim3(16, 16), dim3(256), 0, stream,
                       Xh, W1t, b1, H1, (float*)nullptr, 1024, 64);
    hipLaunchKernelGGL(gemm_relu, dim3(16, 16), dim3(256), 0, stream,
                       H1, W2t, b2, H2, (float*)nullptr, 1024, 1024);
    hipLaunchKernelGGL(gemm_relu, dim3(8, 16), dim3(256), 0, stream,
                       H2, W3t, b3, (_Float16*)nullptr, Zb, 512, 1024);
    hipLaunchKernelGGL(pdhg_mfma, dim3(BATCH / 8), dim3(512), 0, stream,
                       Zb, X, s1f, s2f, tau, out);
}

// Round 14
// 321.055 us; speedup vs baseline: 1.1846x; 1.0487x over previous
//
#include <hip/hip_runtime.h>

// ---------------------------------------------------------------------------
// MatchNet: 3-layer MLP (relu after every layer) -> batched PDHG LP solve.
// Shapes: X[2048,64], W1[64,1024], W2[1024,1024], W3[1024,512], S[64,512].
// Output: x [2048,512] fp32.
//
// R14: (a) power-iteration row-reduce via sum16(DPP) + LDS partial store
// (bit-identical combine order) -- removes 16 serialized swizzle+bpermute
// chains per step (R13 evidence: prep straggler unchanged at 122us after
// u-loop fix -> the sum64 chains were the cost). (b) power relocated from
// prep into GEMM2's dispatch (extra grid column; needs only S, feeds pdhg)
// so the straggler hides under the longest GEMM. pdhg frozen at R12.
// ---------------------------------------------------------------------------

typedef _Float16 half8 __attribute__((ext_vector_type(8)));
typedef __fp16 fp16x2 __attribute__((ext_vector_type(2)));
typedef __fp16 fp16x4 __attribute__((ext_vector_type(4)));
typedef float floatx4 __attribute__((ext_vector_type(4)));
typedef float floatx2 __attribute__((ext_vector_type(2)));

#define BATCH 2048
#define NITERS 60
#define XBS 520   // delta-xbar LDS row stride in halves
#define YLS 72    // delta-ylo  LDS row stride in halves

typedef const __attribute__((address_space(1))) unsigned int* gptr_as1;
typedef __attribute__((address_space(3))) unsigned int* lptr_as3;
__device__ __forceinline__ void gl_lds16(const _Float16* g, _Float16* s) {
    __builtin_amdgcn_global_load_lds((gptr_as1)g, (lptr_as3)s, 16, 0, 0);
}
__device__ __forceinline__ floatx2 pmax0(floatx2 a) {
    return __builtin_elementwise_max(a, floatx2{0.f, 0.f});
}

// ---- cross-lane sums: DPP (VALU pipe) within 16-lane rows ----
template <int CTRL>
__device__ __forceinline__ float dpp_addf(float x) {
    int y = __builtin_amdgcn_update_dpp(0, __builtin_bit_cast(int, x), CTRL, 0xf, 0xf, true);
    return x + __builtin_bit_cast(float, y);
}
__device__ __forceinline__ float sum16(float x) {
    x = dpp_addf<0xB1>(x);    // quad_perm(1,0,3,2): xor 1
    x = dpp_addf<0x4E>(x);    // quad_perm(2,3,0,1): xor 2
    x = dpp_addf<0x124>(x);   // row_ror:4
    x = dpp_addf<0x128>(x);   // row_ror:8 -> full 16-lane sum in all lanes
    return x;
}
__device__ __forceinline__ float sum64(float x) {
    x = sum16(x);
    x += __builtin_bit_cast(float, __builtin_amdgcn_ds_swizzle(__builtin_bit_cast(int, x), 0x401F)); // xor16
    x += __shfl_xor(x, 32, 64);   // cross-half combine
    return x;
}

// ---------------- power iteration for tau, 256-thread variant ------------------
// Row-reduce: sum16 (VALU DPP) -> 4 group-partials stored to pp -> 4-value add
// in combine order (p0+p1)+(p2+p3) == old sum64 order -> tau bit-identical.
__device__ void power_256(const float* __restrict__ S, float* __restrict__ tau_g) {
    __shared__ float vv[512], ww[64], redp[4];
    __shared__ float pp[4][16][4];
    int t = threadIdx.x, wv = t >> 6, ln = t & 63;
    int lm = ln & 15, q = ln >> 4;
    unsigned long long rm0 = 0, rm1 = 0, cm0 = 0, cm1 = 0;
    for (int rr = 0; rr < 8; rr++) {
        float v0[8], v1[8];
#pragma unroll
        for (int e = 0; e < 8; e++) {
            v0[e] = S[(wv * 16 + rr) * 512 + e * 64 + ln];
            v1[e] = S[(wv * 16 + 8 + rr) * 512 + e * 64 + ln];
        }
#pragma unroll
        for (int e = 0; e < 8; e++) {
            if (v0[e] != 0.f) rm0 |= 1ull << (rr * 8 + e);
            if (v1[e] != 0.f) rm1 |= 1ull << (rr * 8 + e);
        }
    }
    for (int jb = 0; jb < 4; jb++) {
        float c0[16], c1[16];
#pragma unroll
        for (int jj = 0; jj < 16; jj++) {
            c0[jj] = S[(jb * 16 + jj) * 512 + t];
            c1[jj] = S[(jb * 16 + jj) * 512 + t + 256];
        }
#pragma unroll
        for (int jj = 0; jj < 16; jj++) {
            if (c0[jj] != 0.f) cm0 |= 1ull << (jb * 16 + jj);
            if (c1[jj] != 0.f) cm1 |= 1ull << (jb * 16 + jj);
        }
    }
    vv[t] = 0.044194173824159216f;        // 1/sqrt(512)
    vv[t + 256] = 0.044194173824159216f;
    __syncthreads();
    for (int s = 0; s <= 30; s++) {
        float ve[8];
#pragma unroll
        for (int e = 0; e < 8; e++) ve[e] = vv[e * 64 + ln];
        float pr[16];
#pragma unroll
        for (int rr = 0; rr < 8; rr++) {
            unsigned int b0 = (unsigned int)(rm0 >> (rr * 8)) & 0xffu;
            unsigned int b1 = (unsigned int)(rm1 >> (rr * 8)) & 0xffu;
            float a0 = 0.f, a1 = 0.f;
#pragma unroll
            for (int e = 0; e < 8; e++) {
                a0 += (b0 >> e & 1) ? ve[e] : 0.f;
                a1 += (b1 >> e & 1) ? ve[e] : 0.f;
            }
            pr[rr] = a0; pr[8 + rr] = a1;
        }
        // 16-lane partial sums (VALU only), then 4 group partials to LDS
#pragma unroll
        for (int rr = 0; rr < 16; rr++) {
            float v = sum16(pr[rr]);
            if (lm == rr) pp[wv][rr][q] = v;
        }
        __syncthreads();
        if (ln < 16) {
            floatx4 pv = *(const floatx4*)&pp[wv][ln][0];
            ww[wv * 16 + ln] = (pv.x + pv.y) + (pv.z + pv.w);
        }
        __syncthreads();
        floatx4 w4[16];
#pragma unroll
        for (int jj = 0; jj < 16; jj++) w4[jj] = *(const floatx4*)&ww[jj * 4];
        float u0 = vv[t], u1 = vv[t + 256];
#pragma unroll
        for (int j = 0; j < 64; j++) {
            float wj = w4[j >> 2][j & 3];
            u0 += (cm0 >> j & 1) ? wj : 0.f;
            u1 += (cm1 >> j & 1) ? wj : 0.f;
        }
        float n2 = (s == 30) ? (vv[t] * u0 + vv[t + 256] * u1) : (u0 * u0 + u1 * u1);
        n2 = sum64(n2);
        if (ln == 0) redp[wv] = n2;
        __syncthreads();
        float tot = (redp[0] + redp[1]) + (redp[2] + redp[3]);
        if (s == 30) {
            if (t == 0) tau_g[0] = 0.9f / sqrtf(tot);
            return;
        }
        float sq = sqrtf(tot);
        vv[t] = u0 / sq;
        vv[t + 256] = u1 / sq;
        __syncthreads();
    }
}

// ---------------- merged prep: cast X, W transposes, S frags -------------------
__global__ __launch_bounds__(256) void prep(
    const float* __restrict__ X, _Float16* __restrict__ Xh,
    const float* __restrict__ W1, _Float16* __restrict__ W1t,
    const float* __restrict__ W2, _Float16* __restrict__ W2t,
    const float* __restrict__ W3, _Float16* __restrict__ W3t,
    const float* __restrict__ S, _Float16* __restrict__ s1f,
    _Float16* __restrict__ s2f) {
    __shared__ float tile[32][33];
    int tid = threadIdx.x;
    int bid = blockIdx.x;
    if (bid < 512) {
        int i = bid * 256 + tid;
        Xh[i] = (_Float16)X[i];
        return;
    }
    bid -= 512;
    if (bid < 1600) {   // transpose+cast W[K][N] -> Wt[N][K]
        const float* W; _Float16* Wt; int K, N, b;
        if (bid < 64)        { W = W1; Wt = W1t; K = 64;   N = 1024; b = bid; }
        else if (bid < 1088) { W = W2; Wt = W2t; K = 1024; N = 1024; b = bid - 64; }
        else                 { W = W3; Wt = W3t; K = 1024; N = 512;  b = bid - 1088; }
        int nbx = N / 32;
        int n0 = (b % nbx) * 32, k0 = (b / nbx) * 32;
        int tx = tid & 31, ty = tid >> 5;
#pragma unroll
        for (int i = 0; i < 4; i++)
            tile[ty + i * 8][tx] = W[(size_t)(k0 + ty + i * 8) * N + n0 + tx];
        __syncthreads();
#pragma unroll
        for (int i = 0; i < 4; i++)
            Wt[(size_t)(n0 + ty + i * 8) * K + k0 + tx] = (_Float16)tile[tx][ty + i * 8];
        return;
    }
    bid -= 1600;
    int i = bid * 256 + tid;       // 0 .. 65535
    if (i < 4 * 16 * 64 * 8) {     // s1f: B-frag of S^T, k-axis in pi-order
        int j = i & 7, lane = (i >> 3) & 63, kk = (i >> 9) & 15, wc = i >> 13;
        int p = kk * 32 + (lane >> 4) * 8 + j;
        int lmc = (p & 127) >> 3, tc = p & 7;
        int c = (p >> 7) * 128 + tc * 16 + lmc;       // pi^-1
        int m = wc * 16 + (lane & 15);
        s1f[i] = (_Float16)S[m * 512 + c];
    } else {                       // s2f: B-frag of S (k = combos)
        int i2 = i - 4 * 16 * 64 * 8;
        int j = i2 & 7, lane = (i2 >> 3) & 63, c = (i2 >> 9) & 1,
            tt = (i2 >> 10) & 7, wc = i2 >> 13;
        int kc = c * 32 + (lane >> 4) * 8 + j;
        int n = wc * 128 + tt * 16 + (lane & 15);
        s2f[i2] = (_Float16)S[kc * 512 + n];
    }
}

// ---------------- GEMM: out = relu(A[M,K] @ W[K,N] + bias), f16 in, fp32 acc ---
// Blocks with bn >= N are power-iteration carriers (only on the launch that
// passes Sp != nullptr): block (x = N/64, y = 0) runs power_256, others exit.
__global__ __launch_bounds__(256) void gemm_relu(
    const _Float16* __restrict__ A, const _Float16* __restrict__ Wt,
    const float* __restrict__ bias, _Float16* __restrict__ outh,
    float* __restrict__ outf, int N, int K,
    const float* __restrict__ Sp, float* __restrict__ tau_g) {
    __shared__ __align__(16) _Float16 As[128 * 32];
    __shared__ __align__(16) _Float16 Bs[64 * 32];
    int tid = threadIdx.x;
    int bm = blockIdx.y * 128;
    int bn = blockIdx.x * 64;
    if (bn >= N) {
        if (blockIdx.y == 0 && Sp) power_256(Sp, tau_g);
        return;
    }
    int w = tid >> 6, l = tid & 63;
    int wr = w >> 1, wc = w & 1;
    int lm = l & 15, q = l >> 4;
    floatx4 acc[4][2] = {};

    int sr = l >> 2;
    int sc = (l & 3) * 8;
    const _Float16* ag0 = A + (size_t)(bm + w * 32 + sr) * K + sc;
    const _Float16* ag1 = A + (size_t)(bm + w * 32 + 16 + sr) * K + sc;
    _Float16* as0 = &As[(w * 32) * 32];
    _Float16* as1 = &As[(w * 32 + 16) * 32];
    const _Float16* bg = Wt + (size_t)(bn + w * 16 + sr) * K + sc;
    _Float16* bs = &Bs[(w * 16) * 32];

    for (int k0 = 0; k0 < K; k0 += 32) {
        gl_lds16(ag0 + k0, as0);
        gl_lds16(ag1 + k0, as1);
        gl_lds16(bg + k0, bs);
        __syncthreads();
        half8 af[4], bf[2];
#pragma unroll
        for (int mt = 0; mt < 4; mt++)
            af[mt] = *(const half8*)&As[(wr * 64 + mt * 16 + lm) * 32 + q * 8];
#pragma unroll
        for (int nt = 0; nt < 2; nt++)
            bf[nt] = *(const half8*)&Bs[(wc * 32 + nt * 16 + lm) * 32 + q * 8];
#pragma unroll
        for (int mt = 0; mt < 4; mt++)
#pragma unroll
            for (int nt = 0; nt < 2; nt++)
                acc[mt][nt] = __builtin_amdgcn_mfma_f32_16x16x32_f16(
                    af[mt], bf[nt], acc[mt][nt], 0, 0, 0);
        __syncthreads();
    }
#pragma unroll
    for (int nt = 0; nt < 2; nt++) {
        int col = bn + wc * 32 + nt * 16 + lm;
        float bv = bias[col];
#pragma unroll
        for (int mt = 0; mt < 4; mt++) {
#pragma unroll
            for (int v = 0; v < 4; v++) {
                int row = bm + wr * 64 + mt * 16 + q * 4 + v;
                float val = fmaxf(acc[mt][nt][v] + bv, 0.f);
                if (outh) outh[(size_t)row * N + col] = (_Float16)val;
                else      outf[(size_t)row * N + col] = val;
            }
        }
    }
}

// ---------------- Delta-form MFMA PDHG, 8 waves, 3 barriers, 60 iterations -----
__global__ __launch_bounds__(512, 2) void pdhg_mfma(
    const float* __restrict__ Zb, const float* __restrict__ Xf,
    const _Float16* __restrict__ s1f, const _Float16* __restrict__ s2f,
    const float* __restrict__ tau_p, float* __restrict__ out) {
    __shared__ __align__(16) _Float16 xb_d[16 * XBS];
    __shared__ __align__(16) _Float16 yl_d[16 * YLS];
    __shared__ __align__(16) float red[16][8];
    int tid = threadIdx.x;
    int wave = tid >> 6, p = wave >> 1, s = wave & 1;
    int l = tid & 63, lm = l & 15, q = l >> 4;
    int b0 = blockIdx.x * 8;
    bool act = (q < 2);

    half8 s1[16], s2[4][2];
#pragma unroll
    for (int k = 0; k < 16; k++)
        s1[k] = *(const half8*)&s1f[((p * 16 + k) * 64 + l) * 8];
#pragma unroll
    for (int tt = 0; tt < 4; tt++)
#pragma unroll
        for (int c = 0; c < 2; c++)
            s2[tt][c] = *(const half8*)&s2f[(((p * 8 + s * 4 + tt) * 2 + c) * 64 + l) * 8];

    floatx2 z2[2][4], x2[2][4], xb2[2][4], yh2[2][4], d2[2][4];
    floatx2 ylo2[2], Bc2[2];
    floatx4 a1p[4] = {};
    floatx4 acc2[4] = {};
    float tau = tau_p[0];
    float sig = tau;
#pragma unroll
    for (int vp = 0; vp < 2; vp++) {
        int r0 = b0 + ((q * 4 + 2 * vp) & 7);
        int r1 = b0 + ((q * 4 + 2 * vp + 1) & 7);
        Bc2[vp] = floatx2{Xf[r0 * 64 + p * 16 + lm], Xf[r1 * 64 + p * 16 + lm]};
        ylo2[vp] = floatx2{0.f, 0.f};
#pragma unroll
        for (int tt = 0; tt < 4; tt++) {
            int cc = p * 128 + (s * 4 + tt) * 16 + lm;
            z2[vp][tt] = floatx2{Zb[(size_t)r0 * 512 + cc], Zb[(size_t)r1 * 512 + cc]};
            x2[vp][tt] = floatx2{0.f, 0.f};
            xb2[vp][tt] = floatx2{0.f, 0.f};
            yh2[vp][tt] = floatx2{0.f, 0.f};
        }
    }
    {
        half8 hz = {0, 0, 0, 0, 0, 0, 0, 0};
        for (int i = tid; i < (16 * XBS) / 8; i += 512)
            *(half8*)&xb_d[i * 8] = hz;
        for (int i = tid; i < 16 * YLS; i += 512)
            yl_d[i] = (_Float16)0.f;
    }
    __syncthreads();

#pragma unroll 1
    for (int it = 0; it < NITERS; ++it) {
#pragma unroll
        for (int k = 0; k < 16; k++) {
            half8 ad = *(const half8*)&xb_d[lm * XBS + k * 32 + q * 8];
            a1p[k & 3] = __builtin_amdgcn_mfma_f32_16x16x32_f16(ad, s1[k], a1p[k & 3], 0, 0, 0);
        }
        floatx4 a1 = (a1p[0] + a1p[1]) + (a1p[2] + a1p[3]);
#pragma unroll
        for (int vp = 0; vp < 2; vp++) {
            floatx2 av = (vp == 0) ? floatx2{a1.x, a1.y} : floatx2{a1.z, a1.w};
            floatx2 yv = pmax0(ylo2[vp] + sig * (av - Bc2[vp]));
            floatx2 dy = yv - ylo2[vp];
            ylo2[vp] = yv;
            if (act && vp == s) {
                fp16x2 pk = __builtin_amdgcn_cvt_pkrtz(dy.x, dy.y);
                int a0 = (q * 4 + 2 * vp) * YLS + p * 16 + lm;
                yl_d[a0] = (_Float16)pk[0];
                yl_d[a0 + YLS] = (_Float16)pk[1];
            }
        }
        __syncthreads();   // [A]
        half8 a2d[2];
#pragma unroll
        for (int c = 0; c < 2; c++)
            a2d[c] = *(const half8*)&yl_d[lm * YLS + c * 32 + q * 8];
#pragma unroll
        for (int tt = 0; tt < 4; tt++)
#pragma unroll
            for (int c = 0; c < 2; c++)
                acc2[tt] = __builtin_amdgcn_mfma_f32_16x16x32_f16(a2d[c], s2[tt][c], acc2[tt], 0, 0, 0);
        floatx2 pn2[2] = {floatx2{0.f, 0.f}, floatx2{0.f, 0.f}};
#pragma unroll
        for (int vp = 0; vp < 2; vp++)
#pragma unroll
            for (int tt = 0; tt < 4; tt++) {
                floatx2 accp = (vp == 0) ? floatx2{acc2[tt].x, acc2[tt].y}
                                         : floatx2{acc2[tt].z, acc2[tt].w};
                yh2[vp][tt] = pmax0(yh2[vp][tt] - sig * xb2[vp][tt]);
                floatx2 kty = accp - yh2[vp][tt];
                floatx2 dd = (x2[vp][tt] - tau * kty) + (tau - z2[vp][tt]);
                d2[vp][tt] = dd;
                pn2[vp] += dd * dd;
            }
        float pn[4] = {pn2[0].x, pn2[0].y, pn2[1].x, pn2[1].y};
#pragma unroll
        for (int v = 0; v < 4; v++) pn[v] = sum16(pn[v]);   // DPP, VALU-pipe
        if (lm == 0)
#pragma unroll
            for (int v = 0; v < 4; v++) red[q * 4 + v][wave] = pn[v];
        __syncthreads();   // [B]
        floatx2 sc2[2];
#pragma unroll
        for (int vp = 0; vp < 2; vp++)
#pragma unroll
            for (int c = 0; c < 2; c++) {
                int v = 2 * vp + c;
                floatx4 r0 = *(const floatx4*)&red[q * 4 + v][0];
                floatx4 r1 = *(const floatx4*)&red[q * 4 + v][4];
                floatx4 rr = r0 + r1;
                float n2 = (rr.x + rr.y) + (rr.z + rr.w);
                float sv = fmaxf(1.f - tau * rsqrtf(fmaxf(n2, 1e-24f)), 0.f);
                if (c == 0) sc2[vp].x = sv; else sc2[vp].y = sv;
            }
#pragma unroll
        for (int vp = 0; vp < 2; vp++) {
#pragma unroll
            for (int tt = 0; tt < 4; tt++) {
                floatx2 xn = z2[vp][tt] + sc2[vp] * d2[vp][tt];
                floatx2 xbn = 2.f * xn - x2[vp][tt];
                d2[vp][tt] = xbn - xb2[vp][tt];   // reuse d2 as delta
                x2[vp][tt] = xn;
                xb2[vp][tt] = xbn;
            }
            if (act) {
#pragma unroll
                for (int c = 0; c < 2; c++) {
                    fp16x2 p0 = __builtin_amdgcn_cvt_pkrtz(
                        (c == 0) ? d2[vp][0].x : d2[vp][0].y,
                        (c == 0) ? d2[vp][1].x : d2[vp][1].y);
                    fp16x2 p1 = __builtin_amdgcn_cvt_pkrtz(
                        (c == 0) ? d2[vp][2].x : d2[vp][2].y,
                        (c == 0) ? d2[vp][3].x : d2[vp][3].y);
                    fp16x4 hd = __builtin_shufflevector(p0, p1, 0, 1, 2, 3);
                    int v = 2 * vp + c;
                    *(fp16x4*)&xb_d[(q * 4 + v) * XBS + p * 128 + lm * 8 + s * 4] = hd;
                }
            }
        }
        __syncthreads();   // [C]
    }
    if (act)
#pragma unroll
        for (int vp = 0; vp < 2; vp++)
#pragma unroll
            for (int tt = 0; tt < 4; tt++) {
                int cc = p * 128 + (s * 4 + tt) * 16 + lm;
                out[(size_t)(b0 + q * 4 + 2 * vp) * 512 + cc] = x2[vp][tt].x;
                out[(size_t)(b0 + q * 4 + 2 * vp + 1) * 512 + cc] = x2[vp][tt].y;
            }
}

// ---------------------------------------------------------------------------
extern "C" void kernel_launch(void* const* d_in, const int* in_sizes, int n_in,
                              void* d_out, int out_size, void* d_ws, size_t ws_size,
                              hipStream_t stream) {
    const float* X  = (const float*)d_in[0];
    const float* W1 = (const float*)d_in[1];
    const float* b1 = (const float*)d_in[2];
    const float* W2 = (const float*)d_in[3];
    const float* b2 = (const float*)d_in[4];
    const float* W3 = (const float*)d_in[5];
    const float* b3 = (const float*)d_in[6];
    const float* S  = (const float*)d_in[7];
    float* out = (float*)d_out;

    char* ws = (char*)d_ws;
    size_t off = 0;
    auto alloc = [&](size_t bytes) {
        void* p = ws + off;
        off += (bytes + 255) & ~(size_t)255;
        return p;
    };
    _Float16* Xh  = (_Float16*)alloc((size_t)BATCH * 64 * 2);
    _Float16* W1t = (_Float16*)alloc((size_t)64 * 1024 * 2);
    _Float16* W2t = (_Float16*)alloc((size_t)1024 * 1024 * 2);
    _Float16* W3t = (_Float16*)alloc((size_t)1024 * 512 * 2);
    _Float16* H1  = (_Float16*)alloc((size_t)BATCH * 1024 * 2);
    _Float16* H2  = (_Float16*)alloc((size_t)BATCH * 1024 * 2);
    float*    Zb  = (float*)alloc((size_t)BATCH * 512 * 4);
    _Float16* s1f = (_Float16*)alloc((size_t)4 * 16 * 64 * 8 * 2);
    _Float16* s2f = (_Float16*)alloc((size_t)4 * 8 * 2 * 64 * 8 * 2);
    float*    tau = (float*)alloc(256);

    hipLaunchKernelGGL(prep, dim3(2368), dim3(256), 0, stream,
                       X, Xh, W1, W1t, W2, W2t, W3, W3t, S, s1f, s2f);
    hipLaunchKernelGGL(gemm_relu, dim3(16, 16), dim3(256), 0, stream,
                       Xh, W1t, b1, H1, (float*)nullptr, 1024, 64,
                       (const float*)nullptr, (float*)nullptr);
    hipLaunchKernelGGL(gemm_relu, dim3(17, 16), dim3(256), 0, stream,
                       H1, W2t, b2, H2, (float*)nullptr, 1024, 1024, S, tau);
    hipLaunchKernelGGL(gemm_relu, dim3(8, 16), dim3(256), 0, stream,
                       H2, W3t, b3, (_Float16*)nullptr, Zb, 512, 1024,
                       (const float*)nullptr, (float*)nullptr);
    hipLaunchKernelGGL(pdhg_mfma, dim3(BATCH / 8), dim3(512), 0, stream,
                       Zb, X, s1f, s2f, tau, out);
}

// Round 15
// 231.057 us; speedup vs baseline: 1.6460x; 1.3895x over previous
//
#include <hip/hip_runtime.h>

// ---------------------------------------------------------------------------
// MatchNet: 3-layer MLP (relu after every layer) -> batched PDHG LP solve.
// Shapes: X[2048,64], W1[64,1024], W2[1024,1024], W3[1024,512], S[64,512].
// Output: x [2048,512] fp32.
//
// R15: power iteration reduced EXACTLY to 64-dim via the Gram matrix
// G = S S^T (w_k = S v_k; n^2 = w'Gw + 2|w|^2 + 1; L^2 = |w_30|^2 + 1).
// G built from row bitmasks (ballot + popcount, integer-exact). Kills the
// 512-dim multi-barrier step structure that stayed ~100us through two fix
// attempts (R13/R14 evidence). Carrier block in GEMM2 unchanged; pdhg frozen.
// ---------------------------------------------------------------------------

typedef _Float16 half8 __attribute__((ext_vector_type(8)));
typedef __fp16 fp16x2 __attribute__((ext_vector_type(2)));
typedef __fp16 fp16x4 __attribute__((ext_vector_type(4)));
typedef float floatx4 __attribute__((ext_vector_type(4)));
typedef float floatx2 __attribute__((ext_vector_type(2)));

#define BATCH 2048
#define NITERS 60
#define XBS 520   // delta-xbar LDS row stride in halves
#define YLS 72    // delta-ylo  LDS row stride in halves

typedef const __attribute__((address_space(1))) unsigned int* gptr_as1;
typedef __attribute__((address_space(3))) unsigned int* lptr_as3;
__device__ __forceinline__ void gl_lds16(const _Float16* g, _Float16* s) {
    __builtin_amdgcn_global_load_lds((gptr_as1)g, (lptr_as3)s, 16, 0, 0);
}
__device__ __forceinline__ floatx2 pmax0(floatx2 a) {
    return __builtin_elementwise_max(a, floatx2{0.f, 0.f});
}

// ---- cross-lane sums: DPP (VALU pipe) within 16-lane rows ----
template <int CTRL>
__device__ __forceinline__ float dpp_addf(float x) {
    int y = __builtin_amdgcn_update_dpp(0, __builtin_bit_cast(int, x), CTRL, 0xf, 0xf, true);
    return x + __builtin_bit_cast(float, y);
}
__device__ __forceinline__ float sum16(float x) {
    x = dpp_addf<0xB1>(x);    // quad_perm(1,0,3,2): xor 1
    x = dpp_addf<0x4E>(x);    // quad_perm(2,3,0,1): xor 2
    x = dpp_addf<0x124>(x);   // row_ror:4
    x = dpp_addf<0x128>(x);   // row_ror:8 -> full 16-lane sum in all lanes
    return x;
}
__device__ __forceinline__ float sum64(float x) {
    x = sum16(x);
    x += __builtin_bit_cast(float, __builtin_amdgcn_ds_swizzle(__builtin_bit_cast(int, x), 0x401F)); // xor16
    x += __shfl_xor(x, 32, 64);   // cross-half combine
    return x;
}

// ---------------- 64-dim power iteration for tau (one 256-thread block) --------
// Exact reduction of the reference 512-dim recursion: w_k = S v_k;
//   n_k = sqrt(w'Gw + 2|w|^2 + 1);  w_{k+1} = (Gw + w)/n_k;
//   w_0[i] = rowcount_i / sqrt(512);  L = sqrt(|w_30|^2 + 1);  tau = 0.9/L.
__device__ void power_64(const float* __restrict__ S, float* __restrict__ tau_g) {
    __shared__ unsigned long long rowm[64][8];   // row bitmasks of S
    __shared__ float G[64][65];                  // Gram, +1 pad (conflict-free)
    __shared__ float wl[64], pg[4][64];
    int t = threadIdx.x, wv = t >> 6, ln = t & 63;
    // row bitmasks: wave wv handles rows [wv*16, wv*16+16), ballot per 64-col chunk
    for (int rr = 0; rr < 16; rr++) {
        int r = wv * 16 + rr;
        float v[8];
#pragma unroll
        for (int e = 0; e < 8; e++) v[e] = S[r * 512 + e * 64 + ln];
#pragma unroll
        for (int e = 0; e < 8; e++) {
            unsigned long long m = __ballot(v[e] != 0.f);
            if (ln == 0) rowm[r][e] = m;
        }
    }
    __syncthreads();
    // G[i][j] = popcount(row_i & row_j): 16 entries per thread
    for (int k = 0; k < 16; k++) {
        int idx = t * 16 + k;
        int i = idx >> 6, j = idx & 63;
        int cnt = 0;
#pragma unroll
        for (int e = 0; e < 8; e++) cnt += __popcll(rowm[i][e] & rowm[j][e]);
        G[i][j] = (float)cnt;
    }
    if (wv == 0) {   // w0 = S v0 = rowcount/sqrt(512)
        int cnt = 0;
#pragma unroll
        for (int e = 0; e < 8; e++) cnt += __popcll(rowm[ln][e]);
        wl[ln] = (float)cnt * 0.044194173824159216f;
    }
    __syncthreads();
    for (int s = 0; s < 30; s++) {
        // partial (Gw)[ln] over j in [wv*16, wv*16+16)
        float a = 0.f;
#pragma unroll
        for (int jj = 0; jj < 16; jj++) {
            int j = wv * 16 + jj;
            a += G[ln][j] * wl[j];
        }
        pg[wv][ln] = a;
        __syncthreads();
        if (wv == 0) {
            float g = (pg[0][ln] + pg[1][ln]) + (pg[2][ln] + pg[3][ln]);  // (Gw)[ln]
            float wi = wl[ln];
            float s1 = sum64(wi * g);    // w'Gw
            float s2 = sum64(wi * wi);   // |w|^2
            float n = sqrtf(s1 + 2.f * s2 + 1.f);
            wl[ln] = (g + wi) / n;
        }
        __syncthreads();
    }
    if (wv == 0) {
        float wi = wl[ln];
        float s2 = sum64(wi * wi);
        if (ln == 0) tau_g[0] = 0.9f / sqrtf(s2 + 1.f);
    }
}

// ---------------- merged prep: cast X, W transposes, S frags -------------------
__global__ __launch_bounds__(256) void prep(
    const float* __restrict__ X, _Float16* __restrict__ Xh,
    const float* __restrict__ W1, _Float16* __restrict__ W1t,
    const float* __restrict__ W2, _Float16* __restrict__ W2t,
    const float* __restrict__ W3, _Float16* __restrict__ W3t,
    const float* __restrict__ S, _Float16* __restrict__ s1f,
    _Float16* __restrict__ s2f) {
    __shared__ float tile[32][33];
    int tid = threadIdx.x;
    int bid = blockIdx.x;
    if (bid < 512) {
        int i = bid * 256 + tid;
        Xh[i] = (_Float16)X[i];
        return;
    }
    bid -= 512;
    if (bid < 1600) {   // transpose+cast W[K][N] -> Wt[N][K]
        const float* W; _Float16* Wt; int K, N, b;
        if (bid < 64)        { W = W1; Wt = W1t; K = 64;   N = 1024; b = bid; }
        else if (bid < 1088) { W = W2; Wt = W2t; K = 1024; N = 1024; b = bid - 64; }
        else                 { W = W3; Wt = W3t; K = 1024; N = 512;  b = bid - 1088; }
        int nbx = N / 32;
        int n0 = (b % nbx) * 32, k0 = (b / nbx) * 32;
        int tx = tid & 31, ty = tid >> 5;
#pragma unroll
        for (int i = 0; i < 4; i++)
            tile[ty + i * 8][tx] = W[(size_t)(k0 + ty + i * 8) * N + n0 + tx];
        __syncthreads();
#pragma unroll
        for (int i = 0; i < 4; i++)
            Wt[(size_t)(n0 + ty + i * 8) * K + k0 + tx] = (_Float16)tile[tx][ty + i * 8];
        return;
    }
    bid -= 1600;
    int i = bid * 256 + tid;       // 0 .. 65535
    if (i < 4 * 16 * 64 * 8) {     // s1f: B-frag of S^T, k-axis in pi-order
        int j = i & 7, lane = (i >> 3) & 63, kk = (i >> 9) & 15, wc = i >> 13;
        int p = kk * 32 + (lane >> 4) * 8 + j;
        int lmc = (p & 127) >> 3, tc = p & 7;
        int c = (p >> 7) * 128 + tc * 16 + lmc;       // pi^-1
        int m = wc * 16 + (lane & 15);
        s1f[i] = (_Float16)S[m * 512 + c];
    } else {                       // s2f: B-frag of S (k = combos)
        int i2 = i - 4 * 16 * 64 * 8;
        int j = i2 & 7, lane = (i2 >> 3) & 63, c = (i2 >> 9) & 1,
            tt = (i2 >> 10) & 7, wc = i2 >> 13;
        int kc = c * 32 + (lane >> 4) * 8 + j;
        int n = wc * 128 + tt * 16 + (lane & 15);
        s2f[i2] = (_Float16)S[kc * 512 + n];
    }
}

// ---------------- GEMM: out = relu(A[M,K] @ W[K,N] + bias), f16 in, fp32 acc ---
// Blocks with bn >= N: block (x = N/64, y = 0) runs power_64 when Sp != null.
__global__ __launch_bounds__(256) void gemm_relu(
    const _Float16* __restrict__ A, const _Float16* __restrict__ Wt,
    const float* __restrict__ bias, _Float16* __restrict__ outh,
    float* __restrict__ outf, int N, int K,
    const float* __restrict__ Sp, float* __restrict__ tau_g) {
    __shared__ __align__(16) _Float16 As[128 * 32];
    __shared__ __align__(16) _Float16 Bs[64 * 32];
    int tid = threadIdx.x;
    int bm = blockIdx.y * 128;
    int bn = blockIdx.x * 64;
    if (bn >= N) {
        if (blockIdx.y == 0 && Sp) power_64(Sp, tau_g);
        return;
    }
    int w = tid >> 6, l = tid & 63;
    int wr = w >> 1, wc = w & 1;
    int lm = l & 15, q = l >> 4;
    floatx4 acc[4][2] = {};

    int sr = l >> 2;
    int sc = (l & 3) * 8;
    const _Float16* ag0 = A + (size_t)(bm + w * 32 + sr) * K + sc;
    const _Float16* ag1 = A + (size_t)(bm + w * 32 + 16 + sr) * K + sc;
    _Float16* as0 = &As[(w * 32) * 32];
    _Float16* as1 = &As[(w * 32 + 16) * 32];
    const _Float16* bg = Wt + (size_t)(bn + w * 16 + sr) * K + sc;
    _Float16* bs = &Bs[(w * 16) * 32];

    for (int k0 = 0; k0 < K; k0 += 32) {
        gl_lds16(ag0 + k0, as0);
        gl_lds16(ag1 + k0, as1);
        gl_lds16(bg + k0, bs);
        __syncthreads();
        half8 af[4], bf[2];
#pragma unroll
        for (int mt = 0; mt < 4; mt++)
            af[mt] = *(const half8*)&As[(wr * 64 + mt * 16 + lm) * 32 + q * 8];
#pragma unroll
        for (int nt = 0; nt < 2; nt++)
            bf[nt] = *(const half8*)&Bs[(wc * 32 + nt * 16 + lm) * 32 + q * 8];
#pragma unroll
        for (int mt = 0; mt < 4; mt++)
#pragma unroll
            for (int nt = 0; nt < 2; nt++)
                acc[mt][nt] = __builtin_amdgcn_mfma_f32_16x16x32_f16(
                    af[mt], bf[nt], acc[mt][nt], 0, 0, 0);
        __syncthreads();
    }
#pragma unroll
    for (int nt = 0; nt < 2; nt++) {
        int col = bn + wc * 32 + nt * 16 + lm;
        float bv = bias[col];
#pragma unroll
        for (int mt = 0; mt < 4; mt++) {
#pragma unroll
            for (int v = 0; v < 4; v++) {
                int row = bm + wr * 64 + mt * 16 + q * 4 + v;
                float val = fmaxf(acc[mt][nt][v] + bv, 0.f);
                if (outh) outh[(size_t)row * N + col] = (_Float16)val;
                else      outf[(size_t)row * N + col] = val;
            }
        }
    }
}

// ---------------- Delta-form MFMA PDHG, 8 waves, 3 barriers, 60 iterations -----
__global__ __launch_bounds__(512, 2) void pdhg_mfma(
    const float* __restrict__ Zb, const float* __restrict__ Xf,
    const _Float16* __restrict__ s1f, const _Float16* __restrict__ s2f,
    const float* __restrict__ tau_p, float* __restrict__ out) {
    __shared__ __align__(16) _Float16 xb_d[16 * XBS];
    __shared__ __align__(16) _Float16 yl_d[16 * YLS];
    __shared__ __align__(16) float red[16][8];
    int tid = threadIdx.x;
    int wave = tid >> 6, p = wave >> 1, s = wave & 1;
    int l = tid & 63, lm = l & 15, q = l >> 4;
    int b0 = blockIdx.x * 8;
    bool act = (q < 2);

    half8 s1[16], s2[4][2];
#pragma unroll
    for (int k = 0; k < 16; k++)
        s1[k] = *(const half8*)&s1f[((p * 16 + k) * 64 + l) * 8];
#pragma unroll
    for (int tt = 0; tt < 4; tt++)
#pragma unroll
        for (int c = 0; c < 2; c++)
            s2[tt][c] = *(const half8*)&s2f[(((p * 8 + s * 4 + tt) * 2 + c) * 64 + l) * 8];

    floatx2 z2[2][4], x2[2][4], xb2[2][4], yh2[2][4], d2[2][4];
    floatx2 ylo2[2], Bc2[2];
    floatx4 a1p[4] = {};
    floatx4 acc2[4] = {};
    float tau = tau_p[0];
    float sig = tau;
#pragma unroll
    for (int vp = 0; vp < 2; vp++) {
        int r0 = b0 + ((q * 4 + 2 * vp) & 7);
        int r1 = b0 + ((q * 4 + 2 * vp + 1) & 7);
        Bc2[vp] = floatx2{Xf[r0 * 64 + p * 16 + lm], Xf[r1 * 64 + p * 16 + lm]};
        ylo2[vp] = floatx2{0.f, 0.f};
#pragma unroll
        for (int tt = 0; tt < 4; tt++) {
            int cc = p * 128 + (s * 4 + tt) * 16 + lm;
            z2[vp][tt] = floatx2{Zb[(size_t)r0 * 512 + cc], Zb[(size_t)r1 * 512 + cc]};
            x2[vp][tt] = floatx2{0.f, 0.f};
            xb2[vp][tt] = floatx2{0.f, 0.f};
            yh2[vp][tt] = floatx2{0.f, 0.f};
        }
    }
    {
        half8 hz = {0, 0, 0, 0, 0, 0, 0, 0};
        for (int i = tid; i < (16 * XBS) / 8; i += 512)
            *(half8*)&xb_d[i * 8] = hz;
        for (int i = tid; i < 16 * YLS; i += 512)
            yl_d[i] = (_Float16)0.f;
    }
    __syncthreads();

#pragma unroll 1
    for (int it = 0; it < NITERS; ++it) {
#pragma unroll
        for (int k = 0; k < 16; k++) {
            half8 ad = *(const half8*)&xb_d[lm * XBS + k * 32 + q * 8];
            a1p[k & 3] = __builtin_amdgcn_mfma_f32_16x16x32_f16(ad, s1[k], a1p[k & 3], 0, 0, 0);
        }
        floatx4 a1 = (a1p[0] + a1p[1]) + (a1p[2] + a1p[3]);
#pragma unroll
        for (int vp = 0; vp < 2; vp++) {
            floatx2 av = (vp == 0) ? floatx2{a1.x, a1.y} : floatx2{a1.z, a1.w};
            floatx2 yv = pmax0(ylo2[vp] + sig * (av - Bc2[vp]));
            floatx2 dy = yv - ylo2[vp];
            ylo2[vp] = yv;
            if (act && vp == s) {
                fp16x2 pk = __builtin_amdgcn_cvt_pkrtz(dy.x, dy.y);
                int a0 = (q * 4 + 2 * vp) * YLS + p * 16 + lm;
                yl_d[a0] = (_Float16)pk[0];
                yl_d[a0 + YLS] = (_Float16)pk[1];
            }
        }
        __syncthreads();   // [A]
        half8 a2d[2];
#pragma unroll
        for (int c = 0; c < 2; c++)
            a2d[c] = *(const half8*)&yl_d[lm * YLS + c * 32 + q * 8];
#pragma unroll
        for (int tt = 0; tt < 4; tt++)
#pragma unroll
            for (int c = 0; c < 2; c++)
                acc2[tt] = __builtin_amdgcn_mfma_f32_16x16x32_f16(a2d[c], s2[tt][c], acc2[tt], 0, 0, 0);
        floatx2 pn2[2] = {floatx2{0.f, 0.f}, floatx2{0.f, 0.f}};
#pragma unroll
        for (int vp = 0; vp < 2; vp++)
#pragma unroll
            for (int tt = 0; tt < 4; tt++) {
                floatx2 accp = (vp == 0) ? floatx2{acc2[tt].x, acc2[tt].y}
                                         : floatx2{acc2[tt].z, acc2[tt].w};
                yh2[vp][tt] = pmax0(yh2[vp][tt] - sig * xb2[vp][tt]);
                floatx2 kty = accp - yh2[vp][tt];
                floatx2 dd = (x2[vp][tt] - tau * kty) + (tau - z2[vp][tt]);
                d2[vp][tt] = dd;
                pn2[vp] += dd * dd;
            }
        float pn[4] = {pn2[0].x, pn2[0].y, pn2[1].x, pn2[1].y};
#pragma unroll
        for (int v = 0; v < 4; v++) pn[v] = sum16(pn[v]);   // DPP, VALU-pipe
        if (lm == 0)
#pragma unroll
            for (int v = 0; v < 4; v++) red[q * 4 + v][wave] = pn[v];
        __syncthreads();   // [B]
        floatx2 sc2[2];
#pragma unroll
        for (int vp = 0; vp < 2; vp++)
#pragma unroll
            for (int c = 0; c < 2; c++) {
                int v = 2 * vp + c;
                floatx4 r0 = *(const floatx4*)&red[q * 4 + v][0];
                floatx4 r1 = *(const floatx4*)&red[q * 4 + v][4];
                floatx4 rr = r0 + r1;
                float n2 = (rr.x + rr.y) + (rr.z + rr.w);
                float sv = fmaxf(1.f - tau * rsqrtf(fmaxf(n2, 1e-24f)), 0.f);
                if (c == 0) sc2[vp].x = sv; else sc2[vp].y = sv;
            }
#pragma unroll
        for (int vp = 0; vp < 2; vp++) {
#pragma unroll
            for (int tt = 0; tt < 4; tt++) {
                floatx2 xn = z2[vp][tt] + sc2[vp] * d2[vp][tt];
                floatx2 xbn = 2.f * xn - x2[vp][tt];
                d2[vp][tt] = xbn - xb2[vp][tt];   // reuse d2 as delta
                x2[vp][tt] = xn;
                xb2[vp][tt] = xbn;
            }
            if (act) {
#pragma unroll
                for (int c = 0; c < 2; c++) {
                    fp16x2 p0 = __builtin_amdgcn_cvt_pkrtz(
                        (c == 0) ? d2[vp][0].x : d2[vp][0].y,
                        (c == 0) ? d2[vp][1].x : d2[vp][1].y);
                    fp16x2 p1 = __builtin_amdgcn_cvt_pkrtz(
                        (c == 0) ? d2[vp][2].x : d2[vp][2].y,
                        (c == 0) ? d2[vp][3].x : d2[vp][3].y);
                    fp16x4 hd = __builtin_shufflevector(p0, p1, 0, 1, 2, 3);
                    int v = 2 * vp + c;
                    *(fp16x4*)&xb_d[(q * 4 + v) * XBS + p * 128 + lm * 8 + s * 4] = hd;
                }
            }
        }
        __syncthreads();   // [C]
    }
    if (act)
#pragma unroll
        for (int vp = 0; vp < 2; vp++)
#pragma unroll
            for (int tt = 0; tt < 4; tt++) {
                int cc = p * 128 + (s * 4 + tt) * 16 + lm;
                out[(size_t)(b0 + q * 4 + 2 * vp) * 512 + cc] = x2[vp][tt].x;
                out[(size_t)(b0 + q * 4 + 2 * vp + 1) * 512 + cc] = x2[vp][tt].y;
            }
}

// ---------------------------------------------------------------------------
extern "C" void kernel_launch(void* const* d_in, const int* in_sizes, int n_in,
                              void* d_out, int out_size, void* d_ws, size_t ws_size,
                              hipStream_t stream) {
    const float* X  = (const float*)d_in[0];
    const float* W1 = (const float*)d_in[1];
    const float* b1 = (const float*)d_in[2];
    const float* W2 = (const float*)d_in[3];
    const float* b2 = (const float*)d_in[4];
    const float* W3 = (const float*)d_in[5];
    const float* b3 = (const float*)d_in[6];
    const float* S  = (const float*)d_in[7];
    float* out = (float*)d_out;

    char* ws = (char*)d_ws;
    size_t off = 0;
    auto alloc = [&](size_t bytes) {
        void* p = ws + off;
        off += (bytes + 255) & ~(size_t)255;
        return p;
    };
    _Float16* Xh  = (_Float16*)alloc((size_t)BATCH * 64 * 2);
    _Float16* W1t = (_Float16*)alloc((size_t)64 * 1024 * 2);
    _Float16* W2t = (_Float16*)alloc((size_t)1024 * 1024 * 2);
    _Float16* W3t = (_Float16*)alloc((size_t)1024 * 512 * 2);
    _Float16* H1  = (_Float16*)alloc((size_t)BATCH * 1024 * 2);
    _Float16* H2  = (_Float16*)alloc((size_t)BATCH * 1024 * 2);
    float*    Zb  = (float*)alloc((size_t)BATCH * 512 * 4);
    _Float16* s1f = (_Float16*)alloc((size_t)4 * 16 * 64 * 8 * 2);
    _Float16* s2f = (_Float16*)alloc((size_t)4 * 8 * 2 * 64 * 8 * 2);
    float*    tau = (float*)alloc(256);

    hipLaunchKernelGGL(prep, dim3(2368), dim3(256), 0, stream,
                       X, Xh, W1, W1t, W2, W2t, W3, W3t, S, s1f, s2f);
    hipLaunchKernelGGL(gemm_relu, dim3(16, 16), dim3(256), 0, stream,
                       Xh, W1t, b1, H1, (float*)nullptr, 1024, 64,
                       (const float*)nullptr, (float*)nullptr);
    hipLaunchKernelGGL(gemm_relu, dim3(17, 16), dim3(256), 0, stream,
                       H1, W2t, b2, H2, (float*)nullptr, 1024, 1024, S, tau);
    hipLaunchKernelGGL(gemm_relu, dim3(8, 16), dim3(256), 0, stream,
                       H2, W3t, b3, (_Float16*)nullptr, Zb, 512, 1024,
                       (const float*)nullptr, (float*)nullptr);
    hipLaunchKernelGGL(pdhg_mfma, dim3(BATCH / 8), dim3(512), 0, stream,
                       Zb, X, s1f, s2f, tau, out);
}